// Round 10
// baseline (1614.244 us; speedup 1.0000x reference)
//
#include <hip/hip_runtime.h>
#include <hip/hip_bf16.h>

#define NN 100000
#define NE 1600000
#define NBN 5000
#define NCOARSE 512
#define NSB 391   // ceil(NN/256) scan blocks

__device__ __forceinline__ unsigned f2ord(float f) {
    unsigned u = __float_as_uint(f);
    return (u & 0x80000000u) ? ~u : (u | 0x80000000u);
}
__device__ __forceinline__ float ord2f(unsigned u) {
    u = (u & 0x80000000u) ? (u & 0x7FFFFFFFu) : ~u;
    return __uint_as_float(u);
}
__device__ __forceinline__ float lrelu(float x) { return x > 0.f ? x : 0.01f * x; }

// ---- mark boundary nodes ----
__global__ __launch_bounds__(256) void k_scatter(const int* __restrict__ bn, unsigned char* __restrict__ isb) {
    int i = blockIdx.x * 256 + threadIdx.x;
    if (i < NBN) isb[bn[i]] = 1;
}

// ---- embed ----
__global__ __launch_bounds__(256) void k_embed(const float* __restrict__ nodes, const unsigned char* __restrict__ isb,
                                               const float* __restrict__ dmean, const float* __restrict__ dstd,
                                               const float* __restrict__ eW, const float* __restrict__ eb,
                                               float* __restrict__ x) {
    __shared__ float sW[448];
    __shared__ float sb[64];
    __shared__ float sm[3], sd[3];
    int t = threadIdx.x;
    for (int i = t; i < 448; i += 256) sW[i] = eW[i];
    if (t < 64) sb[t] = eb[t];
    if (t < 3) { sm[t] = dmean[t]; sd[t] = dstd[t]; }
    __syncthreads();
    int lane = t & 63, wv = t >> 6;
    int w = blockIdx.x * 4 + wv, nw = gridDim.x * 4;
    for (int n = w; n < NN; n += nw) {
        float row[7];
#pragma unroll
        for (int k = 0; k < 7; k++) row[k] = nodes[n * 7 + k];
        if (isb[n]) {
#pragma unroll
            for (int k = 0; k < 3; k++) row[3 + k] = (row[3 + k] - sm[k]) / sd[k];
        }
        float acc = sb[lane];
#pragma unroll
        for (int k = 0; k < 7; k++) acc += row[k] * sW[k * 64 + lane];
        x[n * 64 + lane] = acc;
    }
}

// ---- coords min/max ----
__global__ __launch_bounds__(256) void k_minmax(const float* __restrict__ nodes, unsigned* __restrict__ mn_ord,
                                                unsigned* __restrict__ mx_ord) {
    int tid = blockIdx.x * 256 + threadIdx.x;
    int stride = gridDim.x * 256;
    float mn[3] = {INFINITY, INFINITY, INFINITY};
    float mx[3] = {-INFINITY, -INFINITY, -INFINITY};
    for (int n = tid; n < NN; n += stride) {
#pragma unroll
        for (int k = 0; k < 3; k++) {
            float c = nodes[n * 7 + k];
            mn[k] = fminf(mn[k], c);
            mx[k] = fmaxf(mx[k], c);
        }
    }
#pragma unroll
    for (int off = 32; off; off >>= 1) {
#pragma unroll
        for (int k = 0; k < 3; k++) {
            mn[k] = fminf(mn[k], __shfl_down(mn[k], off));
            mx[k] = fmaxf(mx[k], __shfl_down(mx[k], off));
        }
    }
    if ((threadIdx.x & 63) == 0) {
#pragma unroll
        for (int k = 0; k < 3; k++) {
            atomicMin(&mn_ord[k], f2ord(mn[k]));
            atomicMax(&mx_ord[k], f2ord(mx[k]));
        }
    }
}

// ---- voxel block id ----
__global__ __launch_bounds__(256) void k_bid(const float* __restrict__ nodes, const unsigned* __restrict__ mn_ord,
                                             const unsigned* __restrict__ mx_ord, int* __restrict__ bid) {
    int n = blockIdx.x * 256 + threadIdx.x;
    if (n >= NN) return;
    int g[3];
#pragma unroll
    for (int k = 0; k < 3; k++) {
        float mn = ord2f(mn_ord[k]), mx = ord2f(mx_ord[k]);
        float cell = (mx - mn) / 8.0f;
        int gi = (int)floorf((nodes[n * 7 + k] - mn) / cell);
        gi = gi < 0 ? 0 : (gi > 7 ? 7 : gi);
        g[k] = gi;
    }
    bid[n] = g[0] * 64 + g[1] * 8 + g[2];
}

// ---- h = x@W; a_s = h·A[:64]; a_r = h·A[64:] ----
__global__ __launch_bounds__(256) void k_mm(const float* __restrict__ x, const float* __restrict__ W,
                                            const float* __restrict__ A, float* __restrict__ h,
                                            float* __restrict__ as_, float* __restrict__ ar_, int nrow) {
    __shared__ float sW[4096];
    __shared__ float sA[128];
    int t = threadIdx.x;
    for (int i = t; i < 4096; i += 256) sW[i] = W[i];
    if (t < 128) sA[t] = A[t];
    __syncthreads();
    int lane = t & 63, wv = t >> 6;
    int w = blockIdx.x * 4 + wv, nw = gridDim.x * 4;
    for (int n = w; n < nrow; n += nw) {
        const float* xr = x + (size_t)n * 64;
        float acc = 0.f;
#pragma unroll
        for (int k = 0; k < 64; k++) acc += xr[k] * sW[k * 64 + lane];
        h[(size_t)n * 64 + lane] = acc;
        float va = acc * sA[lane], vr = acc * sA[64 + lane];
#pragma unroll
        for (int off = 32; off; off >>= 1) {
            va += __shfl_down(va, off);
            vr += __shfl_down(vr, off);
        }
        if (lane == 0) { as_[n] = va; ar_[n] = vr; }
    }
}

// ---- CSR by receiver: degree histogram ----
__global__ __launch_bounds__(256) void k_deg(const int* __restrict__ re, unsigned* __restrict__ deg) {
    int e = blockIdx.x * 256 + threadIdx.x;
    if (e < NE) atomicAdd(&deg[re[e]], 1u);
}

__global__ __launch_bounds__(256) void k_scan1(const unsigned* __restrict__ deg, unsigned* __restrict__ rowptr,
                                               unsigned* __restrict__ partial) {
    __shared__ unsigned s[256];
    int t = threadIdx.x, i = blockIdx.x * 256 + t;
    unsigned v = (i < NN) ? deg[i] : 0u;
    s[t] = v;
    __syncthreads();
    for (int off = 1; off < 256; off <<= 1) {
        unsigned u = (t >= off) ? s[t - off] : 0u;
        __syncthreads();
        s[t] += u;
        __syncthreads();
    }
    if (i < NN) rowptr[i] = s[t] - v;
    if (t == 255) partial[blockIdx.x] = s[255];
}

__global__ __launch_bounds__(512) void k_scan2(unsigned* __restrict__ partial) {
    __shared__ unsigned s[512];
    int t = threadIdx.x;
    unsigned v = (t < NSB) ? partial[t] : 0u;
    s[t] = v;
    __syncthreads();
    for (int off = 1; off < 512; off <<= 1) {
        unsigned u = (t >= off) ? s[t - off] : 0u;
        __syncthreads();
        s[t] += u;
        __syncthreads();
    }
    if (t < NSB) partial[t] = s[t] - v;
}

__global__ __launch_bounds__(256) void k_scan3(unsigned* __restrict__ rowptr, const unsigned* __restrict__ partial,
                                               unsigned* __restrict__ cursor) {
    int t = threadIdx.x, i = blockIdx.x * 256 + t;
    if (i < NN) {
        unsigned r = rowptr[i] + partial[blockIdx.x];
        rowptr[i] = r;
        cursor[i] = r;
    }
    if (i == 0) rowptr[NN] = NE;
}

__global__ __launch_bounds__(256) void k_fill(const int* __restrict__ se, const int* __restrict__ re,
                                              unsigned* __restrict__ cursor, int* __restrict__ csr_s) {
    int e = blockIdx.x * 256 + threadIdx.x;
    if (e >= NE) return;
    unsigned pos = atomicAdd(&cursor[re[e]], 1u);
    csr_s[pos] = se[e];
}

// ---- fused fine GAT (online softmax, CSR, index prefetch) ----
__global__ __launch_bounds__(256) void k_gat1(const unsigned* __restrict__ rowptr, const int* __restrict__ csr_s,
                                              const float* __restrict__ as_, const float* __restrict__ ar_,
                                              const float* __restrict__ h, float* __restrict__ o_raw) {
    int t = threadIdx.x, lane = t & 63, wv = t >> 6;
    int r = blockIdx.x * 4 + wv;
    int g = lane >> 4, fl = lane & 15;
    int p0 = rowptr[r], p1 = rowptr[r + 1];
    float arj = ar_[r];
    float m = -INFINITY, ss = 0.f;
    float a0 = 0.f, a1 = 0.f, a2 = 0.f, a3 = 0.f;
    int p = p0 + g;
    int s = (p < p1) ? csr_s[p] : 0;
    while (p < p1) {
        int pn = p + 4;
        int sn = (pn < p1) ? csr_s[pn] : 0;
        float sc = lrelu(as_[s] + arj);
        const float4 hv = *(const float4*)(h + (size_t)s * 64 + fl * 4);
        float newm = fmaxf(m, sc);
        float scale = __expf(m - newm);
        float w = __expf(sc - newm);
        ss = ss * scale + w;
        a0 = a0 * scale + w * hv.x;
        a1 = a1 * scale + w * hv.y;
        a2 = a2 * scale + w * hv.z;
        a3 = a3 * scale + w * hv.w;
        m = newm;
        p = pn;
        s = sn;
    }
#pragma unroll
    for (int off = 16; off < 64; off <<= 1) {
        float m2 = __shfl_xor(m, off);
        float ss2 = __shfl_xor(ss, off);
        float b0 = __shfl_xor(a0, off), b1 = __shfl_xor(a1, off);
        float b2 = __shfl_xor(a2, off), b3 = __shfl_xor(a3, off);
        float M = fmaxf(m, m2);
        float e1 = (M == -INFINITY) ? 0.f : __expf(m - M);
        float e2 = (M == -INFINITY) ? 0.f : __expf(m2 - M);
        ss = ss * e1 + ss2 * e2;
        a0 = a0 * e1 + b0 * e2;
        a1 = a1 * e1 + b1 * e2;
        a2 = a2 * e1 + b2 * e2;
        a3 = a3 * e1 + b3 * e2;
        m = M;
    }
    if (g == 0) {
        float inv = ss > 0.f ? 1.f / ss : 0.f;
        float4 v = make_float4(a0 * inv, a1 * inv, a2 * inv, a3 * inv);
        *(float4*)(o_raw + (size_t)r * 64 + fl * 4) = v;
    }
}

// ---- column stats over o_raw (512-block grid) ----
__global__ __launch_bounds__(256) void k_stats2(const float* __restrict__ o_raw,
                                                float* __restrict__ colsum, float* __restrict__ colsq) {
    __shared__ float l1[4][64], l2[4][64];
    int t = threadIdx.x, lane = t & 63, wv = t >> 6;
    int w = blockIdx.x * 4 + wv, nw = gridDim.x * 4;
    float cs = 0.f, cq = 0.f;
    for (int n = w; n < NN; n += nw) {
        float v = o_raw[(size_t)n * 64 + lane];
        cs += v;
        cq += v * v;
    }
    l1[wv][lane] = cs;
    l2[wv][lane] = cq;
    __syncthreads();
    if (wv == 0) {
        float a = l1[0][lane] + l1[1][lane] + l1[2][lane] + l1[3][lane];
        float b = l2[0][lane] + l2[1][lane] + l2[2][lane] + l2[3][lane];
        unsafeAtomicAdd(&colsum[lane], a);
        unsafeAtomicAdd(&colsq[lane], b);
    }
}

__global__ void k_meanvar(const float* __restrict__ colsum, const float* __restrict__ colsq, float* __restrict__ mr) {
    int t = threadIdx.x;
    if (t < 64) {
        float mean = colsum[t] / (float)NN;
        float var = colsq[t] / (float)NN - mean * mean;
        mr[t] = mean;
        mr[64 + t] = rsqrtf(var + 1e-5f);
    }
}

// ---- graphnorm + silu + res1 (pure streaming, NO atomics) ----
__global__ __launch_bounds__(256) void k_apply(const float* __restrict__ o_raw, const float* __restrict__ res1,
                                               const float* __restrict__ gamma, const float* __restrict__ beta,
                                               const float* __restrict__ mr, float* __restrict__ x1) {
    int t = threadIdx.x, lane = t & 63;
    int n = blockIdx.x * 4 + (t >> 6);
    if (n >= NN) return;
    float v = o_raw[(size_t)n * 64 + lane];
    float y = gamma[lane] * (v - mr[lane]) * mr[64 + lane] + beta[lane];
    float s = y / (1.f + __expf(-y));
    x1[(size_t)n * 64 + lane] = s + res1[(size_t)n * 64 + lane];
}

// ---- CSR by bid: histogram / scan / fill ----
__global__ __launch_bounds__(256) void k_deg2(const int* __restrict__ bid, unsigned* __restrict__ deg2) {
    int n = blockIdx.x * 256 + threadIdx.x;
    if (n < NN) atomicAdd(&deg2[bid[n]], 1u);
}

__global__ __launch_bounds__(512) void k_scanb(const unsigned* __restrict__ deg2, unsigned* __restrict__ rowptr2,
                                               unsigned* __restrict__ cursor2) {
    __shared__ unsigned s[512];
    int t = threadIdx.x;
    unsigned v = deg2[t];
    s[t] = v;
    __syncthreads();
    for (int off = 1; off < 512; off <<= 1) {
        unsigned u = (t >= off) ? s[t - off] : 0u;
        __syncthreads();
        s[t] += u;
        __syncthreads();
    }
    rowptr2[t] = s[t] - v;
    cursor2[t] = s[t] - v;
    if (t == 0) rowptr2[NCOARSE] = NN;
}

__global__ __launch_bounds__(256) void k_fill2(const int* __restrict__ bid, unsigned* __restrict__ cursor2,
                                               int* __restrict__ csr_n) {
    int n = blockIdx.x * 256 + threadIdx.x;
    if (n >= NN) return;
    unsigned pos = atomicAdd(&cursor2[bid[n]], 1u);
    csr_n[pos] = n;
}

// ---- cnodes: x2[b] = (sum of x1 rows in voxel b) / sqrt(size+1e-10) ----
__global__ __launch_bounds__(256) void k_cn(const unsigned* __restrict__ rowptr2, const int* __restrict__ csr_n,
                                            const float* __restrict__ x1, float* __restrict__ x2) {
    __shared__ float acc_s[4][64];
    int t = threadIdx.x, lane = t & 63, wv = t >> 6;
    int b = blockIdx.x;
    int p0 = rowptr2[b], p1 = rowptr2[b + 1];
    float acc = 0.f;
    int p = p0 + wv;
    int n = (p < p1) ? csr_n[p] : 0;
    while (p < p1) {
        int pn = p + 4;
        int nn = (pn < p1) ? csr_n[pn] : 0;
        acc += x1[(size_t)n * 64 + lane];
        p = pn;
        n = nn;
    }
    acc_s[wv][lane] = acc;
    __syncthreads();
    if (wv == 0) {
        float tot = acc_s[0][lane] + acc_s[1][lane] + acc_s[2][lane] + acc_s[3][lane];
        x2[b * 64 + lane] = tot / sqrtf((float)(p1 - p0) + 1e-10f);
    }
}

// ---- coarse edge-count matrix (ROW = receiver) ----
__global__ __launch_bounds__(256) void k_cnt(const int* __restrict__ se, const int* __restrict__ re,
                                             const int* __restrict__ bid, unsigned* __restrict__ cnt) {
    int e = blockIdx.x * 256 + threadIdx.x;
    if (e >= NE) return;
    atomicAdd(&cnt[bid[re[e]] * NCOARSE + bid[se[e]]], 1u);
}

// ---- dense coarse GAT: block per receiver j, lane-parallel weights ----
__global__ __launch_bounds__(256) void k_cgat(const float* __restrict__ h, const float* __restrict__ as_,
                                              const float* __restrict__ ar_, const unsigned* __restrict__ cnt,
                                              float* __restrict__ g) {
    __shared__ float red[256];
    __shared__ float sw[NCOARSE];
    __shared__ float acc_s[4][64];
    int t = threadIdx.x, lane = t & 63, wv = t >> 6;
    int j = blockIdx.x;
    float arj = ar_[j];
    // phase 1: weights (lane-parallel, coalesced cnt/as_ reads)
    unsigned c0 = cnt[j * NCOARSE + t], c1 = cnt[j * NCOARSE + t + 256];
    float s0 = lrelu(as_[t] + arj), s1 = lrelu(as_[t + 256] + arj);
    float v0 = c0 ? s0 : -INFINITY, v1 = c1 ? s1 : -INFINITY;
    red[t] = fmaxf(v0, v1);
    __syncthreads();
    for (int off = 128; off; off >>= 1) {
        if (t < off) red[t] = fmaxf(red[t], red[t + off]);
        __syncthreads();
    }
    float m = red[0];
    __syncthreads();
    float w0 = c0 ? (float)c0 * __expf(s0 - m) : 0.f;
    float w1 = c1 ? (float)c1 * __expf(s1 - m) : 0.f;
    sw[t] = w0;
    sw[t + 256] = w1;
    red[t] = w0 + w1;
    __syncthreads();
    for (int off = 128; off; off >>= 1) {
        if (t < off) red[t] += red[t + off];
        __syncthreads();
    }
    float ss = red[0];
    // phase 2: acc[f] = sum_i sw[i]*h[i][f], 128 i's per wave
    float acc = 0.f;
    int i0 = wv * 128;
#pragma unroll 4
    for (int i = i0; i < i0 + 128; i++) acc += sw[i] * h[i * 64 + lane];
    acc_s[wv][lane] = acc;
    __syncthreads();
    if (wv == 0) {
        float tot = acc_s[0][lane] + acc_s[1][lane] + acc_s[2][lane] + acc_s[3][lane];
        g[j * 64 + lane] = ss > 0.f ? tot / ss : 0.f;
    }
}

// ---- coarse graphnorm + silu + residual ----
__global__ __launch_bounds__(64) void k_cnorm(const float* __restrict__ gin, const float* __restrict__ gamma,
                                              const float* __restrict__ beta, const float* __restrict__ res,
                                              float* __restrict__ xout) {
    int f = blockIdx.x, lane = threadIdx.x;
    float v[8];
    float s = 0.f, q = 0.f;
#pragma unroll
    for (int k = 0; k < 8; k++) {
        v[k] = gin[(lane + 64 * k) * 64 + f];
        s += v[k];
        q += v[k] * v[k];
    }
#pragma unroll
    for (int off = 32; off; off >>= 1) {
        s += __shfl_down(s, off);
        q += __shfl_down(q, off);
    }
    s = __shfl(s, 0);
    q = __shfl(q, 0);
    float mean = s / 512.f, var = q / 512.f - mean * mean, rstd = rsqrtf(var + 1e-5f);
    float gf = gamma[f], bf = beta[f];
#pragma unroll
    for (int k = 0; k < 8; k++) {
        float y = gf * (v[k] - mean) * rstd + bf;
        float si = y / (1.f + __expf(-y));
        int idx = (lane + 64 * k) * 64 + f;
        xout[idx] = si + res[idx];
    }
}

// ---- final reduction ----
__global__ __launch_bounds__(256) void k_final(const float* __restrict__ g3, const float* __restrict__ x3,
                                               const float* __restrict__ dW, const float* __restrict__ db,
                                               float* __restrict__ out) {
    __shared__ float l[4];
    int t = threadIdx.x;
    float p = 0.f;
    for (int idx = t; idx < NCOARSE * 64; idx += 256) p += (g3[idx] + x3[idx]) * dW[idx & 63];
#pragma unroll
    for (int off = 32; off; off >>= 1) p += __shfl_down(p, off);
    if ((t & 63) == 0) l[t >> 6] = p;
    __syncthreads();
    if (t == 0) out[0] = l[0] + l[1] + l[2] + l[3] + db[0];
}

extern "C" void kernel_launch(void* const* d_in, const int* in_sizes, int n_in,
                              void* d_out, int out_size, void* d_ws, size_t ws_size,
                              hipStream_t stream) {
    const float* nodes = (const float*)d_in[0];
    const int* senders = (const int*)d_in[1];
    const int* receivers = (const int*)d_in[2];
    const int* bnodes = (const int*)d_in[3];
    const float* dmean = (const float*)d_in[4];
    const float* dstd = (const float*)d_in[5];
    const float* eW = (const float*)d_in[6];
    const float* eb = (const float*)d_in[7];
    const float* W1 = (const float*)d_in[8];
    const float* A1 = (const float*)d_in[9];
    const float* gamma1 = (const float*)d_in[10];
    const float* beta1 = (const float*)d_in[11];
    const float* W2 = (const float*)d_in[12];
    const float* A2 = (const float*)d_in[13];
    const float* gamma2 = (const float*)d_in[14];
    const float* beta2 = (const float*)d_in[15];
    const float* W3 = (const float*)d_in[16];
    const float* A3 = (const float*)d_in[17];
    const float* dW = (const float*)d_in[18];
    const float* db = (const float*)d_in[19];
    float* out = (float*)d_out;

    char* p = (char*)d_ws;
    auto alloc = [&](size_t b) { char* r = p; p += (b + 255) & ~(size_t)255; return r; };
    float* x_emb = (float*)alloc((size_t)NN * 64 * 4);   // res1
    float* h1 = (float*)alloc((size_t)NN * 64 * 4);      // reused as x1 after gat1
    float* o_raw = (float*)alloc((size_t)NN * 64 * 4);
    float* as1 = (float*)alloc(NN * 4);
    float* ar1 = (float*)alloc(NN * 4);
    int* bid = (int*)alloc(NN * 4);
    unsigned char* isb = (unsigned char*)alloc(NN);
    float* colsum = (float*)alloc(64 * 4);
    float* colsq = (float*)alloc(64 * 4);
    float* mr = (float*)alloc(128 * 4);
    unsigned* mn_ord = (unsigned*)alloc(3 * 4);
    unsigned* mx_ord = (unsigned*)alloc(3 * 4);
    unsigned* cnt = (unsigned*)alloc((size_t)NCOARSE * NCOARSE * 4);
    float* x2 = (float*)alloc(NCOARSE * 64 * 4);   // res2
    float* h2 = (float*)alloc(NCOARSE * 64 * 4);
    float* as2 = (float*)alloc(NCOARSE * 4);
    float* ar2 = (float*)alloc(NCOARSE * 4);
    float* gat2 = (float*)alloc(NCOARSE * 64 * 4);
    float* x3 = (float*)alloc(NCOARSE * 64 * 4);   // res3
    float* h3 = (float*)alloc(NCOARSE * 64 * 4);
    float* as3 = (float*)alloc(NCOARSE * 4);
    float* ar3 = (float*)alloc(NCOARSE * 4);
    float* gat3 = (float*)alloc(NCOARSE * 64 * 4);
    unsigned* deg = (unsigned*)alloc(NN * 4);
    unsigned* rowptr = (unsigned*)alloc((NN + 1) * 4);
    unsigned* cursor = (unsigned*)alloc(NN * 4);
    unsigned* partial = (unsigned*)alloc(512 * 4);
    int* csr_s = (int*)alloc((size_t)NE * 4);
    unsigned* deg2 = (unsigned*)alloc(NCOARSE * 4);
    unsigned* rowptr2 = (unsigned*)alloc((NCOARSE + 1) * 4);
    unsigned* cursor2 = (unsigned*)alloc(NCOARSE * 4);
    int* csr_n = (int*)alloc(NN * 4);

    hipMemsetAsync(isb, 0, NN, stream);
    hipMemsetAsync(colsum, 0, 64 * 4, stream);
    hipMemsetAsync(colsq, 0, 64 * 4, stream);
    hipMemsetAsync(mn_ord, 0xFF, 12, stream);
    hipMemsetAsync(mx_ord, 0, 12, stream);
    hipMemsetAsync(cnt, 0, (size_t)NCOARSE * NCOARSE * 4, stream);
    hipMemsetAsync(deg, 0, NN * 4, stream);
    hipMemsetAsync(deg2, 0, NCOARSE * 4, stream);

    k_scatter<<<(NBN + 255) / 256, 256, 0, stream>>>(bnodes, isb);
    k_embed<<<2048, 256, 0, stream>>>(nodes, isb, dmean, dstd, eW, eb, x_emb);
    k_minmax<<<512, 256, 0, stream>>>(nodes, mn_ord, mx_ord);
    k_bid<<<(NN + 255) / 256, 256, 0, stream>>>(nodes, mn_ord, mx_ord, bid);
    k_deg<<<(NE + 255) / 256, 256, 0, stream>>>(receivers, deg);
    k_scan1<<<NSB, 256, 0, stream>>>(deg, rowptr, partial);
    k_scan2<<<1, 512, 0, stream>>>(partial);
    k_scan3<<<NSB, 256, 0, stream>>>(rowptr, partial, cursor);
    k_fill<<<(NE + 255) / 256, 256, 0, stream>>>(senders, receivers, cursor, csr_s);
    k_deg2<<<(NN + 255) / 256, 256, 0, stream>>>(bid, deg2);
    k_scanb<<<1, 512, 0, stream>>>(deg2, rowptr2, cursor2);
    k_fill2<<<(NN + 255) / 256, 256, 0, stream>>>(bid, cursor2, csr_n);
    k_cnt<<<(NE + 255) / 256, 256, 0, stream>>>(senders, receivers, bid, cnt);
    k_mm<<<2048, 256, 0, stream>>>(x_emb, W1, A1, h1, as1, ar1, NN);
    k_gat1<<<NN / 4, 256, 0, stream>>>(rowptr, csr_s, as1, ar1, h1, o_raw);
    k_stats2<<<512, 256, 0, stream>>>(o_raw, colsum, colsq);
    k_meanvar<<<1, 64, 0, stream>>>(colsum, colsq, mr);
    k_apply<<<NN / 4, 256, 0, stream>>>(o_raw, x_emb, gamma1, beta1, mr, h1);
    k_cn<<<NCOARSE, 256, 0, stream>>>(rowptr2, csr_n, h1, x2);
    k_mm<<<NCOARSE / 4, 256, 0, stream>>>(x2, W2, A2, h2, as2, ar2, NCOARSE);
    k_cgat<<<NCOARSE, 256, 0, stream>>>(h2, as2, ar2, cnt, gat2);
    k_cnorm<<<64, 64, 0, stream>>>(gat2, gamma2, beta2, x2, x3);
    k_mm<<<NCOARSE / 4, 256, 0, stream>>>(x3, W3, A3, h3, as3, ar3, NCOARSE);
    k_cgat<<<NCOARSE, 256, 0, stream>>>(h3, as3, ar3, cnt, gat3);
    k_final<<<1, 256, 0, stream>>>(gat3, x3, dW, db, out);
}

// Round 11
// 1060.361 us; speedup vs baseline: 1.5224x; 1.5224x over previous
//
#include <hip/hip_runtime.h>
#include <hip/hip_bf16.h>

#define NN 100000
#define NE 1600000
#define NBN 5000
#define NCOARSE 512
#define NSB 391   // ceil(NN/256) scan blocks

__device__ __forceinline__ unsigned f2ord(float f) {
    unsigned u = __float_as_uint(f);
    return (u & 0x80000000u) ? ~u : (u | 0x80000000u);
}
__device__ __forceinline__ float ord2f(unsigned u) {
    u = (u & 0x80000000u) ? (u & 0x7FFFFFFFu) : ~u;
    return __uint_as_float(u);
}
__device__ __forceinline__ float lrelu(float x) { return x > 0.f ? x : 0.01f * x; }

// ---- mark boundary nodes ----
__global__ __launch_bounds__(256) void k_scatter(const int* __restrict__ bn, unsigned char* __restrict__ isb) {
    int i = blockIdx.x * 256 + threadIdx.x;
    if (i < NBN) isb[bn[i]] = 1;
}

// ---- embed ----
__global__ __launch_bounds__(256) void k_embed(const float* __restrict__ nodes, const unsigned char* __restrict__ isb,
                                               const float* __restrict__ dmean, const float* __restrict__ dstd,
                                               const float* __restrict__ eW, const float* __restrict__ eb,
                                               float* __restrict__ x) {
    __shared__ float sW[448];
    __shared__ float sb[64];
    __shared__ float sm[3], sd[3];
    int t = threadIdx.x;
    for (int i = t; i < 448; i += 256) sW[i] = eW[i];
    if (t < 64) sb[t] = eb[t];
    if (t < 3) { sm[t] = dmean[t]; sd[t] = dstd[t]; }
    __syncthreads();
    int lane = t & 63, wv = t >> 6;
    int w = blockIdx.x * 4 + wv, nw = gridDim.x * 4;
    for (int n = w; n < NN; n += nw) {
        float row[7];
#pragma unroll
        for (int k = 0; k < 7; k++) row[k] = nodes[n * 7 + k];
        if (isb[n]) {
#pragma unroll
            for (int k = 0; k < 3; k++) row[3 + k] = (row[3 + k] - sm[k]) / sd[k];
        }
        float acc = sb[lane];
#pragma unroll
        for (int k = 0; k < 7; k++) acc += row[k] * sW[k * 64 + lane];
        x[n * 64 + lane] = acc;
    }
}

// ---- coords min/max ----
__global__ __launch_bounds__(256) void k_minmax(const float* __restrict__ nodes, unsigned* __restrict__ mn_ord,
                                                unsigned* __restrict__ mx_ord) {
    int tid = blockIdx.x * 256 + threadIdx.x;
    int stride = gridDim.x * 256;
    float mn[3] = {INFINITY, INFINITY, INFINITY};
    float mx[3] = {-INFINITY, -INFINITY, -INFINITY};
    for (int n = tid; n < NN; n += stride) {
#pragma unroll
        for (int k = 0; k < 3; k++) {
            float c = nodes[n * 7 + k];
            mn[k] = fminf(mn[k], c);
            mx[k] = fmaxf(mx[k], c);
        }
    }
#pragma unroll
    for (int off = 32; off; off >>= 1) {
#pragma unroll
        for (int k = 0; k < 3; k++) {
            mn[k] = fminf(mn[k], __shfl_down(mn[k], off));
            mx[k] = fmaxf(mx[k], __shfl_down(mx[k], off));
        }
    }
    if ((threadIdx.x & 63) == 0) {
#pragma unroll
        for (int k = 0; k < 3; k++) {
            atomicMin(&mn_ord[k], f2ord(mn[k]));
            atomicMax(&mx_ord[k], f2ord(mx[k]));
        }
    }
}

// ---- voxel block id ----
__global__ __launch_bounds__(256) void k_bid(const float* __restrict__ nodes, const unsigned* __restrict__ mn_ord,
                                             const unsigned* __restrict__ mx_ord, int* __restrict__ bid) {
    int n = blockIdx.x * 256 + threadIdx.x;
    if (n >= NN) return;
    int g[3];
#pragma unroll
    for (int k = 0; k < 3; k++) {
        float mn = ord2f(mn_ord[k]), mx = ord2f(mx_ord[k]);
        float cell = (mx - mn) / 8.0f;
        int gi = (int)floorf((nodes[n * 7 + k] - mn) / cell);
        gi = gi < 0 ? 0 : (gi > 7 ? 7 : gi);
        g[k] = gi;
    }
    bid[n] = g[0] * 64 + g[1] * 8 + g[2];
}

// ---- h = x@W; a_s = h·A[:64]; a_r = h·A[64:] ----
__global__ __launch_bounds__(256) void k_mm(const float* __restrict__ x, const float* __restrict__ W,
                                            const float* __restrict__ A, float* __restrict__ h,
                                            float* __restrict__ as_, float* __restrict__ ar_, int nrow) {
    __shared__ float sW[4096];
    __shared__ float sA[128];
    int t = threadIdx.x;
    for (int i = t; i < 4096; i += 256) sW[i] = W[i];
    if (t < 128) sA[t] = A[t];
    __syncthreads();
    int lane = t & 63, wv = t >> 6;
    int w = blockIdx.x * 4 + wv, nw = gridDim.x * 4;
    for (int n = w; n < nrow; n += nw) {
        const float* xr = x + (size_t)n * 64;
        float acc = 0.f;
#pragma unroll
        for (int k = 0; k < 64; k++) acc += xr[k] * sW[k * 64 + lane];
        h[(size_t)n * 64 + lane] = acc;
        float va = acc * sA[lane], vr = acc * sA[64 + lane];
#pragma unroll
        for (int off = 32; off; off >>= 1) {
            va += __shfl_down(va, off);
            vr += __shfl_down(vr, off);
        }
        if (lane == 0) { as_[n] = va; ar_[n] = vr; }
    }
}

// ---- CSR by receiver: degree histogram ----
__global__ __launch_bounds__(256) void k_deg(const int* __restrict__ re, unsigned* __restrict__ deg) {
    int e = blockIdx.x * 256 + threadIdx.x;
    if (e < NE) atomicAdd(&deg[re[e]], 1u);
}

__global__ __launch_bounds__(256) void k_scan1(const unsigned* __restrict__ deg, unsigned* __restrict__ rowptr,
                                               unsigned* __restrict__ partial) {
    __shared__ unsigned s[256];
    int t = threadIdx.x, i = blockIdx.x * 256 + t;
    unsigned v = (i < NN) ? deg[i] : 0u;
    s[t] = v;
    __syncthreads();
    for (int off = 1; off < 256; off <<= 1) {
        unsigned u = (t >= off) ? s[t - off] : 0u;
        __syncthreads();
        s[t] += u;
        __syncthreads();
    }
    if (i < NN) rowptr[i] = s[t] - v;
    if (t == 255) partial[blockIdx.x] = s[255];
}

__global__ __launch_bounds__(512) void k_scan2(unsigned* __restrict__ partial) {
    __shared__ unsigned s[512];
    int t = threadIdx.x;
    unsigned v = (t < NSB) ? partial[t] : 0u;
    s[t] = v;
    __syncthreads();
    for (int off = 1; off < 512; off <<= 1) {
        unsigned u = (t >= off) ? s[t - off] : 0u;
        __syncthreads();
        s[t] += u;
        __syncthreads();
    }
    if (t < NSB) partial[t] = s[t] - v;
}

__global__ __launch_bounds__(256) void k_scan3(unsigned* __restrict__ rowptr, const unsigned* __restrict__ partial,
                                               unsigned* __restrict__ cursor) {
    int t = threadIdx.x, i = blockIdx.x * 256 + t;
    if (i < NN) {
        unsigned r = rowptr[i] + partial[blockIdx.x];
        rowptr[i] = r;
        cursor[i] = r;
    }
    if (i == 0) rowptr[NN] = NE;
}

__global__ __launch_bounds__(256) void k_fill(const int* __restrict__ se, const int* __restrict__ re,
                                              unsigned* __restrict__ cursor, int* __restrict__ csr_s) {
    int e = blockIdx.x * 256 + threadIdx.x;
    if (e >= NE) return;
    unsigned pos = atomicAdd(&cursor[re[e]], 1u);
    csr_s[pos] = se[e];
}

// ---- fused fine GAT (online softmax, CSR, index prefetch) ----
__global__ __launch_bounds__(256) void k_gat1(const unsigned* __restrict__ rowptr, const int* __restrict__ csr_s,
                                              const float* __restrict__ as_, const float* __restrict__ ar_,
                                              const float* __restrict__ h, float* __restrict__ o_raw) {
    int t = threadIdx.x, lane = t & 63, wv = t >> 6;
    int r = blockIdx.x * 4 + wv;
    int g = lane >> 4, fl = lane & 15;
    int p0 = rowptr[r], p1 = rowptr[r + 1];
    float arj = ar_[r];
    float m = -INFINITY, ss = 0.f;
    float a0 = 0.f, a1 = 0.f, a2 = 0.f, a3 = 0.f;
    int p = p0 + g;
    int s = (p < p1) ? csr_s[p] : 0;
    while (p < p1) {
        int pn = p + 4;
        int sn = (pn < p1) ? csr_s[pn] : 0;
        float sc = lrelu(as_[s] + arj);
        const float4 hv = *(const float4*)(h + (size_t)s * 64 + fl * 4);
        float newm = fmaxf(m, sc);
        float scale = __expf(m - newm);
        float w = __expf(sc - newm);
        ss = ss * scale + w;
        a0 = a0 * scale + w * hv.x;
        a1 = a1 * scale + w * hv.y;
        a2 = a2 * scale + w * hv.z;
        a3 = a3 * scale + w * hv.w;
        m = newm;
        p = pn;
        s = sn;
    }
#pragma unroll
    for (int off = 16; off < 64; off <<= 1) {
        float m2 = __shfl_xor(m, off);
        float ss2 = __shfl_xor(ss, off);
        float b0 = __shfl_xor(a0, off), b1 = __shfl_xor(a1, off);
        float b2 = __shfl_xor(a2, off), b3 = __shfl_xor(a3, off);
        float M = fmaxf(m, m2);
        float e1 = (M == -INFINITY) ? 0.f : __expf(m - M);
        float e2 = (M == -INFINITY) ? 0.f : __expf(m2 - M);
        ss = ss * e1 + ss2 * e2;
        a0 = a0 * e1 + b0 * e2;
        a1 = a1 * e1 + b1 * e2;
        a2 = a2 * e1 + b2 * e2;
        a3 = a3 * e1 + b3 * e2;
        m = M;
    }
    if (g == 0) {
        float inv = ss > 0.f ? 1.f / ss : 0.f;
        float4 v = make_float4(a0 * inv, a1 * inv, a2 * inv, a3 * inv);
        *(float4*)(o_raw + (size_t)r * 64 + fl * 4) = v;
    }
}

// ---- column stats over o_raw (512-block grid) ----
__global__ __launch_bounds__(256) void k_stats2(const float* __restrict__ o_raw,
                                                float* __restrict__ colsum, float* __restrict__ colsq) {
    __shared__ float l1[4][64], l2[4][64];
    int t = threadIdx.x, lane = t & 63, wv = t >> 6;
    int w = blockIdx.x * 4 + wv, nw = gridDim.x * 4;
    float cs = 0.f, cq = 0.f;
    for (int n = w; n < NN; n += nw) {
        float v = o_raw[(size_t)n * 64 + lane];
        cs += v;
        cq += v * v;
    }
    l1[wv][lane] = cs;
    l2[wv][lane] = cq;
    __syncthreads();
    if (wv == 0) {
        float a = l1[0][lane] + l1[1][lane] + l1[2][lane] + l1[3][lane];
        float b = l2[0][lane] + l2[1][lane] + l2[2][lane] + l2[3][lane];
        unsafeAtomicAdd(&colsum[lane], a);
        unsafeAtomicAdd(&colsq[lane], b);
    }
}

__global__ void k_meanvar(const float* __restrict__ colsum, const float* __restrict__ colsq, float* __restrict__ mr) {
    int t = threadIdx.x;
    if (t < 64) {
        float mean = colsum[t] / (float)NN;
        float var = colsq[t] / (float)NN - mean * mean;
        mr[t] = mean;
        mr[64 + t] = rsqrtf(var + 1e-5f);
    }
}

// ---- graphnorm + silu + res1 (pure streaming, NO atomics) ----
__global__ __launch_bounds__(256) void k_apply(const float* __restrict__ o_raw, const float* __restrict__ res1,
                                               const float* __restrict__ gamma, const float* __restrict__ beta,
                                               const float* __restrict__ mr, float* __restrict__ x1) {
    int t = threadIdx.x, lane = t & 63;
    int n = blockIdx.x * 4 + (t >> 6);
    if (n >= NN) return;
    float v = o_raw[(size_t)n * 64 + lane];
    float y = gamma[lane] * (v - mr[lane]) * mr[64 + lane] + beta[lane];
    float s = y / (1.f + __expf(-y));
    x1[(size_t)n * 64 + lane] = s + res1[(size_t)n * 64 + lane];
}

// ---- CSR by bid: histogram / scan / fill ----
__global__ __launch_bounds__(256) void k_deg2(const int* __restrict__ bid, unsigned* __restrict__ deg2) {
    int n = blockIdx.x * 256 + threadIdx.x;
    if (n < NN) atomicAdd(&deg2[bid[n]], 1u);
}

__global__ __launch_bounds__(512) void k_scanb(const unsigned* __restrict__ deg2, unsigned* __restrict__ rowptr2,
                                               unsigned* __restrict__ cursor2) {
    __shared__ unsigned s[512];
    int t = threadIdx.x;
    unsigned v = deg2[t];
    s[t] = v;
    __syncthreads();
    for (int off = 1; off < 512; off <<= 1) {
        unsigned u = (t >= off) ? s[t - off] : 0u;
        __syncthreads();
        s[t] += u;
        __syncthreads();
    }
    rowptr2[t] = s[t] - v;
    cursor2[t] = s[t] - v;
    if (t == 0) rowptr2[NCOARSE] = NN;
}

__global__ __launch_bounds__(256) void k_fill2(const int* __restrict__ bid, unsigned* __restrict__ cursor2,
                                               int* __restrict__ csr_n) {
    int n = blockIdx.x * 256 + threadIdx.x;
    if (n >= NN) return;
    unsigned pos = atomicAdd(&cursor2[bid[n]], 1u);
    csr_n[pos] = n;
}

// ---- cnodes accumulate: segmented reduction over bid-sorted csr_n ----
// wave = 64 consecutive csr_n entries, lane = feature; flush per bid-run
__global__ __launch_bounds__(256) void k_cnacc(const int* __restrict__ csr_n, const int* __restrict__ bid,
                                               const float* __restrict__ x1, float* __restrict__ cnacc) {
    int t = threadIdx.x, lane = t & 63, wv = t >> 6;
    int q0 = (blockIdx.x * 4 + wv) * 64;
    if (q0 >= NN) return;
    int q1 = q0 + 64 < NN ? q0 + 64 : NN;
    int n = csr_n[q0];
    int cur = bid[n];
    float acc = 0.f;
    for (int q = q0; q < q1; q++) {
        int n2 = (q + 1 < q1) ? csr_n[q + 1] : 0;
        int b2 = (q + 1 < q1) ? bid[n2] : -1;   // sentinel forces final flush
        acc += x1[(size_t)n * 64 + lane];
        if (b2 != cur) {
            unsafeAtomicAdd(&cnacc[cur * 64 + lane], acc);
            acc = 0.f;
            cur = b2;
        }
        n = n2;
    }
}

// ---- cnodes scale: x2 = cnacc / sqrt(size + 1e-10) ----
__global__ __launch_bounds__(256) void k_cnscale(const float* __restrict__ cnacc, const unsigned* __restrict__ deg2,
                                                 float* __restrict__ x2) {
    int t = threadIdx.x, lane = t & 63;
    int b = blockIdx.x * 4 + (t >> 6);
    if (b >= NCOARSE) return;
    x2[b * 64 + lane] = cnacc[b * 64 + lane] / sqrtf((float)deg2[b] + 1e-10f);
}

// ---- coarse edge-count matrix (ROW = receiver) ----
__global__ __launch_bounds__(256) void k_cnt(const int* __restrict__ se, const int* __restrict__ re,
                                             const int* __restrict__ bid, unsigned* __restrict__ cnt) {
    int e = blockIdx.x * 256 + threadIdx.x;
    if (e >= NE) return;
    atomicAdd(&cnt[bid[re[e]] * NCOARSE + bid[se[e]]], 1u);
}

// ---- dense coarse GAT: block per receiver j, lane-parallel weights ----
__global__ __launch_bounds__(256) void k_cgat(const float* __restrict__ h, const float* __restrict__ as_,
                                              const float* __restrict__ ar_, const unsigned* __restrict__ cnt,
                                              float* __restrict__ g) {
    __shared__ float red[256];
    __shared__ float sw[NCOARSE];
    __shared__ float acc_s[4][64];
    int t = threadIdx.x, lane = t & 63, wv = t >> 6;
    int j = blockIdx.x;
    float arj = ar_[j];
    unsigned c0 = cnt[j * NCOARSE + t], c1 = cnt[j * NCOARSE + t + 256];
    float s0 = lrelu(as_[t] + arj), s1 = lrelu(as_[t + 256] + arj);
    float v0 = c0 ? s0 : -INFINITY, v1 = c1 ? s1 : -INFINITY;
    red[t] = fmaxf(v0, v1);
    __syncthreads();
    for (int off = 128; off; off >>= 1) {
        if (t < off) red[t] = fmaxf(red[t], red[t + off]);
        __syncthreads();
    }
    float m = red[0];
    __syncthreads();
    float w0 = c0 ? (float)c0 * __expf(s0 - m) : 0.f;
    float w1 = c1 ? (float)c1 * __expf(s1 - m) : 0.f;
    sw[t] = w0;
    sw[t + 256] = w1;
    red[t] = w0 + w1;
    __syncthreads();
    for (int off = 128; off; off >>= 1) {
        if (t < off) red[t] += red[t + off];
        __syncthreads();
    }
    float ss = red[0];
    float acc = 0.f;
    int i0 = wv * 128;
#pragma unroll 4
    for (int i = i0; i < i0 + 128; i++) acc += sw[i] * h[i * 64 + lane];
    acc_s[wv][lane] = acc;
    __syncthreads();
    if (wv == 0) {
        float tot = acc_s[0][lane] + acc_s[1][lane] + acc_s[2][lane] + acc_s[3][lane];
        g[j * 64 + lane] = ss > 0.f ? tot / ss : 0.f;
    }
}

// ---- coarse graphnorm + silu + residual ----
__global__ __launch_bounds__(64) void k_cnorm(const float* __restrict__ gin, const float* __restrict__ gamma,
                                              const float* __restrict__ beta, const float* __restrict__ res,
                                              float* __restrict__ xout) {
    int f = blockIdx.x, lane = threadIdx.x;
    float v[8];
    float s = 0.f, q = 0.f;
#pragma unroll
    for (int k = 0; k < 8; k++) {
        v[k] = gin[(lane + 64 * k) * 64 + f];
        s += v[k];
        q += v[k] * v[k];
    }
#pragma unroll
    for (int off = 32; off; off >>= 1) {
        s += __shfl_down(s, off);
        q += __shfl_down(q, off);
    }
    s = __shfl(s, 0);
    q = __shfl(q, 0);
    float mean = s / 512.f, var = q / 512.f - mean * mean, rstd = rsqrtf(var + 1e-5f);
    float gf = gamma[f], bf = beta[f];
#pragma unroll
    for (int k = 0; k < 8; k++) {
        float y = gf * (v[k] - mean) * rstd + bf;
        float si = y / (1.f + __expf(-y));
        int idx = (lane + 64 * k) * 64 + f;
        xout[idx] = si + res[idx];
    }
}

// ---- final reduction ----
__global__ __launch_bounds__(256) void k_final(const float* __restrict__ g3, const float* __restrict__ x3,
                                               const float* __restrict__ dW, const float* __restrict__ db,
                                               float* __restrict__ out) {
    __shared__ float l[4];
    int t = threadIdx.x;
    float p = 0.f;
    for (int idx = t; idx < NCOARSE * 64; idx += 256) p += (g3[idx] + x3[idx]) * dW[idx & 63];
#pragma unroll
    for (int off = 32; off; off >>= 1) p += __shfl_down(p, off);
    if ((t & 63) == 0) l[t >> 6] = p;
    __syncthreads();
    if (t == 0) out[0] = l[0] + l[1] + l[2] + l[3] + db[0];
}

extern "C" void kernel_launch(void* const* d_in, const int* in_sizes, int n_in,
                              void* d_out, int out_size, void* d_ws, size_t ws_size,
                              hipStream_t stream) {
    const float* nodes = (const float*)d_in[0];
    const int* senders = (const int*)d_in[1];
    const int* receivers = (const int*)d_in[2];
    const int* bnodes = (const int*)d_in[3];
    const float* dmean = (const float*)d_in[4];
    const float* dstd = (const float*)d_in[5];
    const float* eW = (const float*)d_in[6];
    const float* eb = (const float*)d_in[7];
    const float* W1 = (const float*)d_in[8];
    const float* A1 = (const float*)d_in[9];
    const float* gamma1 = (const float*)d_in[10];
    const float* beta1 = (const float*)d_in[11];
    const float* W2 = (const float*)d_in[12];
    const float* A2 = (const float*)d_in[13];
    const float* gamma2 = (const float*)d_in[14];
    const float* beta2 = (const float*)d_in[15];
    const float* W3 = (const float*)d_in[16];
    const float* A3 = (const float*)d_in[17];
    const float* dW = (const float*)d_in[18];
    const float* db = (const float*)d_in[19];
    float* out = (float*)d_out;

    char* p = (char*)d_ws;
    auto alloc = [&](size_t b) { char* r = p; p += (b + 255) & ~(size_t)255; return r; };
    float* x_emb = (float*)alloc((size_t)NN * 64 * 4);   // res1
    float* h1 = (float*)alloc((size_t)NN * 64 * 4);      // reused as x1 after gat1
    float* o_raw = (float*)alloc((size_t)NN * 64 * 4);
    float* as1 = (float*)alloc(NN * 4);
    float* ar1 = (float*)alloc(NN * 4);
    int* bid = (int*)alloc(NN * 4);
    unsigned char* isb = (unsigned char*)alloc(NN);
    float* colsum = (float*)alloc(64 * 4);
    float* colsq = (float*)alloc(64 * 4);
    float* mr = (float*)alloc(128 * 4);
    unsigned* mn_ord = (unsigned*)alloc(3 * 4);
    unsigned* mx_ord = (unsigned*)alloc(3 * 4);
    unsigned* cnt = (unsigned*)alloc((size_t)NCOARSE * NCOARSE * 4);
    float* cnacc = (float*)alloc(NCOARSE * 64 * 4);
    float* x2 = (float*)alloc(NCOARSE * 64 * 4);   // res2
    float* h2 = (float*)alloc(NCOARSE * 64 * 4);
    float* as2 = (float*)alloc(NCOARSE * 4);
    float* ar2 = (float*)alloc(NCOARSE * 4);
    float* gat2 = (float*)alloc(NCOARSE * 64 * 4);
    float* x3 = (float*)alloc(NCOARSE * 64 * 4);   // res3
    float* h3 = (float*)alloc(NCOARSE * 64 * 4);
    float* as3 = (float*)alloc(NCOARSE * 4);
    float* ar3 = (float*)alloc(NCOARSE * 4);
    float* gat3 = (float*)alloc(NCOARSE * 64 * 4);
    unsigned* deg = (unsigned*)alloc(NN * 4);
    unsigned* rowptr = (unsigned*)alloc((NN + 1) * 4);
    unsigned* cursor = (unsigned*)alloc(NN * 4);
    unsigned* partial = (unsigned*)alloc(512 * 4);
    int* csr_s = (int*)alloc((size_t)NE * 4);
    unsigned* deg2 = (unsigned*)alloc(NCOARSE * 4);
    unsigned* rowptr2 = (unsigned*)alloc((NCOARSE + 1) * 4);
    unsigned* cursor2 = (unsigned*)alloc(NCOARSE * 4);
    int* csr_n = (int*)alloc(NN * 4);

    hipMemsetAsync(isb, 0, NN, stream);
    hipMemsetAsync(colsum, 0, 64 * 4, stream);
    hipMemsetAsync(colsq, 0, 64 * 4, stream);
    hipMemsetAsync(mn_ord, 0xFF, 12, stream);
    hipMemsetAsync(mx_ord, 0, 12, stream);
    hipMemsetAsync(cnt, 0, (size_t)NCOARSE * NCOARSE * 4, stream);
    hipMemsetAsync(cnacc, 0, NCOARSE * 64 * 4, stream);
    hipMemsetAsync(deg, 0, NN * 4, stream);
    hipMemsetAsync(deg2, 0, NCOARSE * 4, stream);

    k_scatter<<<(NBN + 255) / 256, 256, 0, stream>>>(bnodes, isb);
    k_embed<<<2048, 256, 0, stream>>>(nodes, isb, dmean, dstd, eW, eb, x_emb);
    k_minmax<<<512, 256, 0, stream>>>(nodes, mn_ord, mx_ord);
    k_bid<<<(NN + 255) / 256, 256, 0, stream>>>(nodes, mn_ord, mx_ord, bid);
    k_deg<<<(NE + 255) / 256, 256, 0, stream>>>(receivers, deg);
    k_scan1<<<NSB, 256, 0, stream>>>(deg, rowptr, partial);
    k_scan2<<<1, 512, 0, stream>>>(partial);
    k_scan3<<<NSB, 256, 0, stream>>>(rowptr, partial, cursor);
    k_fill<<<(NE + 255) / 256, 256, 0, stream>>>(senders, receivers, cursor, csr_s);
    k_deg2<<<(NN + 255) / 256, 256, 0, stream>>>(bid, deg2);
    k_scanb<<<1, 512, 0, stream>>>(deg2, rowptr2, cursor2);
    k_fill2<<<(NN + 255) / 256, 256, 0, stream>>>(bid, cursor2, csr_n);
    k_cnt<<<(NE + 255) / 256, 256, 0, stream>>>(senders, receivers, bid, cnt);
    k_mm<<<2048, 256, 0, stream>>>(x_emb, W1, A1, h1, as1, ar1, NN);
    k_gat1<<<NN / 4, 256, 0, stream>>>(rowptr, csr_s, as1, ar1, h1, o_raw);
    k_stats2<<<512, 256, 0, stream>>>(o_raw, colsum, colsq);
    k_meanvar<<<1, 64, 0, stream>>>(colsum, colsq, mr);
    k_apply<<<NN / 4, 256, 0, stream>>>(o_raw, x_emb, gamma1, beta1, mr, h1);
    k_cnacc<<<NSB, 256, 0, stream>>>(csr_n, bid, h1, cnacc);
    k_cnscale<<<NCOARSE / 4, 256, 0, stream>>>(cnacc, deg2, x2);
    k_mm<<<NCOARSE / 4, 256, 0, stream>>>(x2, W2, A2, h2, as2, ar2, NCOARSE);
    k_cgat<<<NCOARSE, 256, 0, stream>>>(h2, as2, ar2, cnt, gat2);
    k_cnorm<<<64, 64, 0, stream>>>(gat2, gamma2, beta2, x2, x3);
    k_mm<<<NCOARSE / 4, 256, 0, stream>>>(x3, W3, A3, h3, as3, ar3, NCOARSE);
    k_cgat<<<NCOARSE, 256, 0, stream>>>(h3, as3, ar3, cnt, gat3);
    k_final<<<1, 256, 0, stream>>>(gat3, x3, dW, db, out);
}

// Round 12
// 967.091 us; speedup vs baseline: 1.6692x; 1.0964x over previous
//
#include <hip/hip_runtime.h>
#include <hip/hip_bf16.h>

#define NN 100000
#define NE 1600000
#define NBN 5000
#define NCOARSE 512
#define NSB 391   // ceil(NN/256) scan blocks
#define NREP 8    // cnt histogram replicas (hot-cell contention split)

__device__ __forceinline__ unsigned f2ord(float f) {
    unsigned u = __float_as_uint(f);
    return (u & 0x80000000u) ? ~u : (u | 0x80000000u);
}
__device__ __forceinline__ float ord2f(unsigned u) {
    u = (u & 0x80000000u) ? (u & 0x7FFFFFFFu) : ~u;
    return __uint_as_float(u);
}
__device__ __forceinline__ float lrelu(float x) { return x > 0.f ? x : 0.01f * x; }

// ---- mark boundary nodes ----
__global__ __launch_bounds__(256) void k_scatter(const int* __restrict__ bn, unsigned char* __restrict__ isb) {
    int i = blockIdx.x * 256 + threadIdx.x;
    if (i < NBN) isb[bn[i]] = 1;
}

// ---- embed ----
__global__ __launch_bounds__(256) void k_embed(const float* __restrict__ nodes, const unsigned char* __restrict__ isb,
                                               const float* __restrict__ dmean, const float* __restrict__ dstd,
                                               const float* __restrict__ eW, const float* __restrict__ eb,
                                               float* __restrict__ x) {
    __shared__ float sW[448];
    __shared__ float sb[64];
    __shared__ float sm[3], sd[3];
    int t = threadIdx.x;
    for (int i = t; i < 448; i += 256) sW[i] = eW[i];
    if (t < 64) sb[t] = eb[t];
    if (t < 3) { sm[t] = dmean[t]; sd[t] = dstd[t]; }
    __syncthreads();
    int lane = t & 63, wv = t >> 6;
    int w = blockIdx.x * 4 + wv, nw = gridDim.x * 4;
    for (int n = w; n < NN; n += nw) {
        float row[7];
#pragma unroll
        for (int k = 0; k < 7; k++) row[k] = nodes[n * 7 + k];
        if (isb[n]) {
#pragma unroll
            for (int k = 0; k < 3; k++) row[3 + k] = (row[3 + k] - sm[k]) / sd[k];
        }
        float acc = sb[lane];
#pragma unroll
        for (int k = 0; k < 7; k++) acc += row[k] * sW[k * 64 + lane];
        x[n * 64 + lane] = acc;
    }
}

// ---- coords min/max ----
__global__ __launch_bounds__(256) void k_minmax(const float* __restrict__ nodes, unsigned* __restrict__ mn_ord,
                                                unsigned* __restrict__ mx_ord) {
    int tid = blockIdx.x * 256 + threadIdx.x;
    int stride = gridDim.x * 256;
    float mn[3] = {INFINITY, INFINITY, INFINITY};
    float mx[3] = {-INFINITY, -INFINITY, -INFINITY};
    for (int n = tid; n < NN; n += stride) {
#pragma unroll
        for (int k = 0; k < 3; k++) {
            float c = nodes[n * 7 + k];
            mn[k] = fminf(mn[k], c);
            mx[k] = fmaxf(mx[k], c);
        }
    }
#pragma unroll
    for (int off = 32; off; off >>= 1) {
#pragma unroll
        for (int k = 0; k < 3; k++) {
            mn[k] = fminf(mn[k], __shfl_down(mn[k], off));
            mx[k] = fmaxf(mx[k], __shfl_down(mx[k], off));
        }
    }
    if ((threadIdx.x & 63) == 0) {
#pragma unroll
        for (int k = 0; k < 3; k++) {
            atomicMin(&mn_ord[k], f2ord(mn[k]));
            atomicMax(&mx_ord[k], f2ord(mx[k]));
        }
    }
}

// ---- voxel block id ----
__global__ __launch_bounds__(256) void k_bid(const float* __restrict__ nodes, const unsigned* __restrict__ mn_ord,
                                             const unsigned* __restrict__ mx_ord, int* __restrict__ bid) {
    int n = blockIdx.x * 256 + threadIdx.x;
    if (n >= NN) return;
    int g[3];
#pragma unroll
    for (int k = 0; k < 3; k++) {
        float mn = ord2f(mn_ord[k]), mx = ord2f(mx_ord[k]);
        float cell = (mx - mn) / 8.0f;
        int gi = (int)floorf((nodes[n * 7 + k] - mn) / cell);
        gi = gi < 0 ? 0 : (gi > 7 ? 7 : gi);
        g[k] = gi;
    }
    bid[n] = g[0] * 64 + g[1] * 8 + g[2];
}

// ---- h = x@W; a_s = h·A[:64]; a_r = h·A[64:] ----
__global__ __launch_bounds__(256) void k_mm(const float* __restrict__ x, const float* __restrict__ W,
                                            const float* __restrict__ A, float* __restrict__ h,
                                            float* __restrict__ as_, float* __restrict__ ar_, int nrow) {
    __shared__ float sW[4096];
    __shared__ float sA[128];
    int t = threadIdx.x;
    for (int i = t; i < 4096; i += 256) sW[i] = W[i];
    if (t < 128) sA[t] = A[t];
    __syncthreads();
    int lane = t & 63, wv = t >> 6;
    int w = blockIdx.x * 4 + wv, nw = gridDim.x * 4;
    for (int n = w; n < nrow; n += nw) {
        const float* xr = x + (size_t)n * 64;
        float acc = 0.f;
#pragma unroll
        for (int k = 0; k < 64; k++) acc += xr[k] * sW[k * 64 + lane];
        h[(size_t)n * 64 + lane] = acc;
        float va = acc * sA[lane], vr = acc * sA[64 + lane];
#pragma unroll
        for (int off = 32; off; off >>= 1) {
            va += __shfl_down(va, off);
            vr += __shfl_down(vr, off);
        }
        if (lane == 0) { as_[n] = va; ar_[n] = vr; }
    }
}

// ---- CSR by receiver: degree histogram ----
__global__ __launch_bounds__(256) void k_deg(const int* __restrict__ re, unsigned* __restrict__ deg) {
    int e = blockIdx.x * 256 + threadIdx.x;
    if (e < NE) atomicAdd(&deg[re[e]], 1u);
}

__global__ __launch_bounds__(256) void k_scan1(const unsigned* __restrict__ deg, unsigned* __restrict__ rowptr,
                                               unsigned* __restrict__ partial) {
    __shared__ unsigned s[256];
    int t = threadIdx.x, i = blockIdx.x * 256 + t;
    unsigned v = (i < NN) ? deg[i] : 0u;
    s[t] = v;
    __syncthreads();
    for (int off = 1; off < 256; off <<= 1) {
        unsigned u = (t >= off) ? s[t - off] : 0u;
        __syncthreads();
        s[t] += u;
        __syncthreads();
    }
    if (i < NN) rowptr[i] = s[t] - v;
    if (t == 255) partial[blockIdx.x] = s[255];
}

__global__ __launch_bounds__(512) void k_scan2(unsigned* __restrict__ partial) {
    __shared__ unsigned s[512];
    int t = threadIdx.x;
    unsigned v = (t < NSB) ? partial[t] : 0u;
    s[t] = v;
    __syncthreads();
    for (int off = 1; off < 512; off <<= 1) {
        unsigned u = (t >= off) ? s[t - off] : 0u;
        __syncthreads();
        s[t] += u;
        __syncthreads();
    }
    if (t < NSB) partial[t] = s[t] - v;
}

__global__ __launch_bounds__(256) void k_scan3(unsigned* __restrict__ rowptr, const unsigned* __restrict__ partial,
                                               unsigned* __restrict__ cursor) {
    int t = threadIdx.x, i = blockIdx.x * 256 + t;
    if (i < NN) {
        unsigned r = rowptr[i] + partial[blockIdx.x];
        rowptr[i] = r;
        cursor[i] = r;
    }
    if (i == 0) rowptr[NN] = NE;
}

__global__ __launch_bounds__(256) void k_fill(const int* __restrict__ se, const int* __restrict__ re,
                                              unsigned* __restrict__ cursor, int* __restrict__ csr_s) {
    int e = blockIdx.x * 256 + threadIdx.x;
    if (e >= NE) return;
    unsigned pos = atomicAdd(&cursor[re[e]], 1u);
    csr_s[pos] = se[e];
}

// ---- fused fine GAT (online softmax, CSR, index prefetch) ----
__global__ __launch_bounds__(256) void k_gat1(const unsigned* __restrict__ rowptr, const int* __restrict__ csr_s,
                                              const float* __restrict__ as_, const float* __restrict__ ar_,
                                              const float* __restrict__ h, float* __restrict__ o_raw) {
    int t = threadIdx.x, lane = t & 63, wv = t >> 6;
    int r = blockIdx.x * 4 + wv;
    int g = lane >> 4, fl = lane & 15;
    int p0 = rowptr[r], p1 = rowptr[r + 1];
    float arj = ar_[r];
    float m = -INFINITY, ss = 0.f;
    float a0 = 0.f, a1 = 0.f, a2 = 0.f, a3 = 0.f;
    int p = p0 + g;
    int s = (p < p1) ? csr_s[p] : 0;
    while (p < p1) {
        int pn = p + 4;
        int sn = (pn < p1) ? csr_s[pn] : 0;
        float sc = lrelu(as_[s] + arj);
        const float4 hv = *(const float4*)(h + (size_t)s * 64 + fl * 4);
        float newm = fmaxf(m, sc);
        float scale = __expf(m - newm);
        float w = __expf(sc - newm);
        ss = ss * scale + w;
        a0 = a0 * scale + w * hv.x;
        a1 = a1 * scale + w * hv.y;
        a2 = a2 * scale + w * hv.z;
        a3 = a3 * scale + w * hv.w;
        m = newm;
        p = pn;
        s = sn;
    }
#pragma unroll
    for (int off = 16; off < 64; off <<= 1) {
        float m2 = __shfl_xor(m, off);
        float ss2 = __shfl_xor(ss, off);
        float b0 = __shfl_xor(a0, off), b1 = __shfl_xor(a1, off);
        float b2 = __shfl_xor(a2, off), b3 = __shfl_xor(a3, off);
        float M = fmaxf(m, m2);
        float e1 = (M == -INFINITY) ? 0.f : __expf(m - M);
        float e2 = (M == -INFINITY) ? 0.f : __expf(m2 - M);
        ss = ss * e1 + ss2 * e2;
        a0 = a0 * e1 + b0 * e2;
        a1 = a1 * e1 + b1 * e2;
        a2 = a2 * e1 + b2 * e2;
        a3 = a3 * e1 + b3 * e2;
        m = M;
    }
    if (g == 0) {
        float inv = ss > 0.f ? 1.f / ss : 0.f;
        float4 v = make_float4(a0 * inv, a1 * inv, a2 * inv, a3 * inv);
        *(float4*)(o_raw + (size_t)r * 64 + fl * 4) = v;
    }
}

// ---- column stats over o_raw (512-block grid) ----
__global__ __launch_bounds__(256) void k_stats2(const float* __restrict__ o_raw,
                                                float* __restrict__ colsum, float* __restrict__ colsq) {
    __shared__ float l1[4][64], l2[4][64];
    int t = threadIdx.x, lane = t & 63, wv = t >> 6;
    int w = blockIdx.x * 4 + wv, nw = gridDim.x * 4;
    float cs = 0.f, cq = 0.f;
    for (int n = w; n < NN; n += nw) {
        float v = o_raw[(size_t)n * 64 + lane];
        cs += v;
        cq += v * v;
    }
    l1[wv][lane] = cs;
    l2[wv][lane] = cq;
    __syncthreads();
    if (wv == 0) {
        float a = l1[0][lane] + l1[1][lane] + l1[2][lane] + l1[3][lane];
        float b = l2[0][lane] + l2[1][lane] + l2[2][lane] + l2[3][lane];
        unsafeAtomicAdd(&colsum[lane], a);
        unsafeAtomicAdd(&colsq[lane], b);
    }
}

__global__ void k_meanvar(const float* __restrict__ colsum, const float* __restrict__ colsq, float* __restrict__ mr) {
    int t = threadIdx.x;
    if (t < 64) {
        float mean = colsum[t] / (float)NN;
        float var = colsq[t] / (float)NN - mean * mean;
        mr[t] = mean;
        mr[64 + t] = rsqrtf(var + 1e-5f);
    }
}

// ---- graphnorm + silu + res1 (pure streaming, NO atomics) ----
__global__ __launch_bounds__(256) void k_apply(const float* __restrict__ o_raw, const float* __restrict__ res1,
                                               const float* __restrict__ gamma, const float* __restrict__ beta,
                                               const float* __restrict__ mr, float* __restrict__ x1) {
    int t = threadIdx.x, lane = t & 63;
    int n = blockIdx.x * 4 + (t >> 6);
    if (n >= NN) return;
    float v = o_raw[(size_t)n * 64 + lane];
    float y = gamma[lane] * (v - mr[lane]) * mr[64 + lane] + beta[lane];
    float s = y / (1.f + __expf(-y));
    x1[(size_t)n * 64 + lane] = s + res1[(size_t)n * 64 + lane];
}

// ---- CSR by bid: histogram / scan / fill ----
__global__ __launch_bounds__(256) void k_deg2(const int* __restrict__ bid, unsigned* __restrict__ deg2) {
    int n = blockIdx.x * 256 + threadIdx.x;
    if (n < NN) atomicAdd(&deg2[bid[n]], 1u);
}

__global__ __launch_bounds__(512) void k_scanb(const unsigned* __restrict__ deg2, unsigned* __restrict__ rowptr2,
                                               unsigned* __restrict__ cursor2) {
    __shared__ unsigned s[512];
    int t = threadIdx.x;
    unsigned v = deg2[t];
    s[t] = v;
    __syncthreads();
    for (int off = 1; off < 512; off <<= 1) {
        unsigned u = (t >= off) ? s[t - off] : 0u;
        __syncthreads();
        s[t] += u;
        __syncthreads();
    }
    rowptr2[t] = s[t] - v;
    cursor2[t] = s[t] - v;
    if (t == 0) rowptr2[NCOARSE] = NN;
}

__global__ __launch_bounds__(256) void k_fill2(const int* __restrict__ bid, unsigned* __restrict__ cursor2,
                                               int* __restrict__ csr_n) {
    int n = blockIdx.x * 256 + threadIdx.x;
    if (n >= NN) return;
    unsigned pos = atomicAdd(&cursor2[bid[n]], 1u);
    csr_n[pos] = n;
}

// ---- cnodes accumulate: segmented reduction over bid-sorted csr_n ----
__global__ __launch_bounds__(256) void k_cnacc(const int* __restrict__ csr_n, const int* __restrict__ bid,
                                               const float* __restrict__ x1, float* __restrict__ cnacc) {
    int t = threadIdx.x, lane = t & 63, wv = t >> 6;
    int q0 = (blockIdx.x * 4 + wv) * 64;
    if (q0 >= NN) return;
    int q1 = q0 + 64 < NN ? q0 + 64 : NN;
    int n = csr_n[q0];
    int cur = bid[n];
    float acc = 0.f;
    for (int q = q0; q < q1; q++) {
        int n2 = (q + 1 < q1) ? csr_n[q + 1] : 0;
        int b2 = (q + 1 < q1) ? bid[n2] : -1;   // sentinel forces final flush
        acc += x1[(size_t)n * 64 + lane];
        if (b2 != cur) {
            unsafeAtomicAdd(&cnacc[cur * 64 + lane], acc);
            acc = 0.f;
            cur = b2;
        }
        n = n2;
    }
}

// ---- cnodes scale: x2 = cnacc / sqrt(size + 1e-10) ----
__global__ __launch_bounds__(256) void k_cnscale(const float* __restrict__ cnacc, const unsigned* __restrict__ deg2,
                                                 float* __restrict__ x2) {
    int t = threadIdx.x, lane = t & 63;
    int b = blockIdx.x * 4 + (t >> 6);
    if (b >= NCOARSE) return;
    x2[b * 64 + lane] = cnacc[b * 64 + lane] / sqrtf((float)deg2[b] + 1e-10f);
}

// ---- coarse edge-count: 8-replica histogram (hot-cell contention /8) ----
__global__ __launch_bounds__(256) void k_cnt(const int* __restrict__ se, const int* __restrict__ re,
                                             const int* __restrict__ bid, unsigned* __restrict__ cntr) {
    int e = blockIdx.x * 256 + threadIdx.x;
    if (e >= NE) return;
    int rep = e & (NREP - 1);
    atomicAdd(&cntr[(size_t)rep * NCOARSE * NCOARSE + bid[re[e]] * NCOARSE + bid[se[e]]], 1u);
}

__global__ __launch_bounds__(256) void k_cntmerge(const unsigned* __restrict__ cntr, unsigned* __restrict__ cnt) {
    int i = blockIdx.x * 256 + threadIdx.x;   // 262144 cells
    unsigned s = 0;
#pragma unroll
    for (int r = 0; r < NREP; r++) s += cntr[(size_t)r * NCOARSE * NCOARSE + i];
    cnt[i] = s;
}

// ---- dense coarse GAT: block per receiver j, lane-parallel weights ----
__global__ __launch_bounds__(256) void k_cgat(const float* __restrict__ h, const float* __restrict__ as_,
                                              const float* __restrict__ ar_, const unsigned* __restrict__ cnt,
                                              float* __restrict__ g) {
    __shared__ float red[256];
    __shared__ float sw[NCOARSE];
    __shared__ float acc_s[4][64];
    int t = threadIdx.x, lane = t & 63, wv = t >> 6;
    int j = blockIdx.x;
    float arj = ar_[j];
    unsigned c0 = cnt[j * NCOARSE + t], c1 = cnt[j * NCOARSE + t + 256];
    float s0 = lrelu(as_[t] + arj), s1 = lrelu(as_[t + 256] + arj);
    float v0 = c0 ? s0 : -INFINITY, v1 = c1 ? s1 : -INFINITY;
    red[t] = fmaxf(v0, v1);
    __syncthreads();
    for (int off = 128; off; off >>= 1) {
        if (t < off) red[t] = fmaxf(red[t], red[t + off]);
        __syncthreads();
    }
    float m = red[0];
    __syncthreads();
    float w0 = c0 ? (float)c0 * __expf(s0 - m) : 0.f;
    float w1 = c1 ? (float)c1 * __expf(s1 - m) : 0.f;
    sw[t] = w0;
    sw[t + 256] = w1;
    red[t] = w0 + w1;
    __syncthreads();
    for (int off = 128; off; off >>= 1) {
        if (t < off) red[t] += red[t + off];
        __syncthreads();
    }
    float ss = red[0];
    float acc = 0.f;
    int i0 = wv * 128;
#pragma unroll 4
    for (int i = i0; i < i0 + 128; i++) acc += sw[i] * h[i * 64 + lane];
    acc_s[wv][lane] = acc;
    __syncthreads();
    if (wv == 0) {
        float tot = acc_s[0][lane] + acc_s[1][lane] + acc_s[2][lane] + acc_s[3][lane];
        g[j * 64 + lane] = ss > 0.f ? tot / ss : 0.f;
    }
}

// ---- coarse graphnorm + silu + residual ----
__global__ __launch_bounds__(64) void k_cnorm(const float* __restrict__ gin, const float* __restrict__ gamma,
                                              const float* __restrict__ beta, const float* __restrict__ res,
                                              float* __restrict__ xout) {
    int f = blockIdx.x, lane = threadIdx.x;
    float v[8];
    float s = 0.f, q = 0.f;
#pragma unroll
    for (int k = 0; k < 8; k++) {
        v[k] = gin[(lane + 64 * k) * 64 + f];
        s += v[k];
        q += v[k] * v[k];
    }
#pragma unroll
    for (int off = 32; off; off >>= 1) {
        s += __shfl_down(s, off);
        q += __shfl_down(q, off);
    }
    s = __shfl(s, 0);
    q = __shfl(q, 0);
    float mean = s / 512.f, var = q / 512.f - mean * mean, rstd = rsqrtf(var + 1e-5f);
    float gf = gamma[f], bf = beta[f];
#pragma unroll
    for (int k = 0; k < 8; k++) {
        float y = gf * (v[k] - mean) * rstd + bf;
        float si = y / (1.f + __expf(-y));
        int idx = (lane + 64 * k) * 64 + f;
        xout[idx] = si + res[idx];
    }
}

// ---- final reduction ----
__global__ __launch_bounds__(256) void k_final(const float* __restrict__ g3, const float* __restrict__ x3,
                                               const float* __restrict__ dW, const float* __restrict__ db,
                                               float* __restrict__ out) {
    __shared__ float l[4];
    int t = threadIdx.x;
    float p = 0.f;
    for (int idx = t; idx < NCOARSE * 64; idx += 256) p += (g3[idx] + x3[idx]) * dW[idx & 63];
#pragma unroll
    for (int off = 32; off; off >>= 1) p += __shfl_down(p, off);
    if ((t & 63) == 0) l[t >> 6] = p;
    __syncthreads();
    if (t == 0) out[0] = l[0] + l[1] + l[2] + l[3] + db[0];
}

extern "C" void kernel_launch(void* const* d_in, const int* in_sizes, int n_in,
                              void* d_out, int out_size, void* d_ws, size_t ws_size,
                              hipStream_t stream) {
    const float* nodes = (const float*)d_in[0];
    const int* senders = (const int*)d_in[1];
    const int* receivers = (const int*)d_in[2];
    const int* bnodes = (const int*)d_in[3];
    const float* dmean = (const float*)d_in[4];
    const float* dstd = (const float*)d_in[5];
    const float* eW = (const float*)d_in[6];
    const float* eb = (const float*)d_in[7];
    const float* W1 = (const float*)d_in[8];
    const float* A1 = (const float*)d_in[9];
    const float* gamma1 = (const float*)d_in[10];
    const float* beta1 = (const float*)d_in[11];
    const float* W2 = (const float*)d_in[12];
    const float* A2 = (const float*)d_in[13];
    const float* gamma2 = (const float*)d_in[14];
    const float* beta2 = (const float*)d_in[15];
    const float* W3 = (const float*)d_in[16];
    const float* A3 = (const float*)d_in[17];
    const float* dW = (const float*)d_in[18];
    const float* db = (const float*)d_in[19];
    float* out = (float*)d_out;

    char* p = (char*)d_ws;
    auto alloc = [&](size_t b) { char* r = p; p += (b + 255) & ~(size_t)255; return r; };
    float* x_emb = (float*)alloc((size_t)NN * 64 * 4);   // res1
    float* h1 = (float*)alloc((size_t)NN * 64 * 4);      // reused as x1 after gat1
    float* o_raw = (float*)alloc((size_t)NN * 64 * 4);
    float* as1 = (float*)alloc(NN * 4);
    float* ar1 = (float*)alloc(NN * 4);
    int* bid = (int*)alloc(NN * 4);
    unsigned char* isb = (unsigned char*)alloc(NN);
    float* colsum = (float*)alloc(64 * 4);
    float* colsq = (float*)alloc(64 * 4);
    float* mr = (float*)alloc(128 * 4);
    unsigned* mn_ord = (unsigned*)alloc(3 * 4);
    unsigned* mx_ord = (unsigned*)alloc(3 * 4);
    unsigned* cnt = (unsigned*)alloc((size_t)NCOARSE * NCOARSE * 4);
    unsigned* cntr = (unsigned*)alloc((size_t)NREP * NCOARSE * NCOARSE * 4);
    float* cnacc = (float*)alloc(NCOARSE * 64 * 4);
    float* x2 = (float*)alloc(NCOARSE * 64 * 4);   // res2
    float* h2 = (float*)alloc(NCOARSE * 64 * 4);
    float* as2 = (float*)alloc(NCOARSE * 4);
    float* ar2 = (float*)alloc(NCOARSE * 4);
    float* gat2 = (float*)alloc(NCOARSE * 64 * 4);
    float* x3 = (float*)alloc(NCOARSE * 64 * 4);   // res3
    float* h3 = (float*)alloc(NCOARSE * 64 * 4);
    float* as3 = (float*)alloc(NCOARSE * 4);
    float* ar3 = (float*)alloc(NCOARSE * 4);
    float* gat3 = (float*)alloc(NCOARSE * 64 * 4);
    unsigned* deg = (unsigned*)alloc(NN * 4);
    unsigned* rowptr = (unsigned*)alloc((NN + 1) * 4);
    unsigned* cursor = (unsigned*)alloc(NN * 4);
    unsigned* partial = (unsigned*)alloc(512 * 4);
    int* csr_s = (int*)alloc((size_t)NE * 4);
    unsigned* deg2 = (unsigned*)alloc(NCOARSE * 4);
    unsigned* rowptr2 = (unsigned*)alloc((NCOARSE + 1) * 4);
    unsigned* cursor2 = (unsigned*)alloc(NCOARSE * 4);
    int* csr_n = (int*)alloc(NN * 4);

    hipMemsetAsync(isb, 0, NN, stream);
    hipMemsetAsync(colsum, 0, 64 * 4, stream);
    hipMemsetAsync(colsq, 0, 64 * 4, stream);
    hipMemsetAsync(mn_ord, 0xFF, 12, stream);
    hipMemsetAsync(mx_ord, 0, 12, stream);
    hipMemsetAsync(cntr, 0, (size_t)NREP * NCOARSE * NCOARSE * 4, stream);
    hipMemsetAsync(cnacc, 0, NCOARSE * 64 * 4, stream);
    hipMemsetAsync(deg, 0, NN * 4, stream);
    hipMemsetAsync(deg2, 0, NCOARSE * 4, stream);

    k_scatter<<<(NBN + 255) / 256, 256, 0, stream>>>(bnodes, isb);
    k_embed<<<2048, 256, 0, stream>>>(nodes, isb, dmean, dstd, eW, eb, x_emb);
    k_minmax<<<512, 256, 0, stream>>>(nodes, mn_ord, mx_ord);
    k_bid<<<(NN + 255) / 256, 256, 0, stream>>>(nodes, mn_ord, mx_ord, bid);
    k_deg<<<(NE + 255) / 256, 256, 0, stream>>>(receivers, deg);
    k_scan1<<<NSB, 256, 0, stream>>>(deg, rowptr, partial);
    k_scan2<<<1, 512, 0, stream>>>(partial);
    k_scan3<<<NSB, 256, 0, stream>>>(rowptr, partial, cursor);
    k_fill<<<(NE + 255) / 256, 256, 0, stream>>>(senders, receivers, cursor, csr_s);
    k_deg2<<<(NN + 255) / 256, 256, 0, stream>>>(bid, deg2);
    k_scanb<<<1, 512, 0, stream>>>(deg2, rowptr2, cursor2);
    k_fill2<<<(NN + 255) / 256, 256, 0, stream>>>(bid, cursor2, csr_n);
    k_cnt<<<(NE + 255) / 256, 256, 0, stream>>>(senders, receivers, bid, cntr);
    k_cntmerge<<<NCOARSE * NCOARSE / 256, 256, 0, stream>>>(cntr, cnt);
    k_mm<<<2048, 256, 0, stream>>>(x_emb, W1, A1, h1, as1, ar1, NN);
    k_gat1<<<NN / 4, 256, 0, stream>>>(rowptr, csr_s, as1, ar1, h1, o_raw);
    k_stats2<<<512, 256, 0, stream>>>(o_raw, colsum, colsq);
    k_meanvar<<<1, 64, 0, stream>>>(colsum, colsq, mr);
    k_apply<<<NN / 4, 256, 0, stream>>>(o_raw, x_emb, gamma1, beta1, mr, h1);
    k_cnacc<<<NSB, 256, 0, stream>>>(csr_n, bid, h1, cnacc);
    k_cnscale<<<NCOARSE / 4, 256, 0, stream>>>(cnacc, deg2, x2);
    k_mm<<<NCOARSE / 4, 256, 0, stream>>>(x2, W2, A2, h2, as2, ar2, NCOARSE);
    k_cgat<<<NCOARSE, 256, 0, stream>>>(h2, as2, ar2, cnt, gat2);
    k_cnorm<<<64, 64, 0, stream>>>(gat2, gamma2, beta2, x2, x3);
    k_mm<<<NCOARSE / 4, 256, 0, stream>>>(x3, W3, A3, h3, as3, ar3, NCOARSE);
    k_cgat<<<NCOARSE, 256, 0, stream>>>(h3, as3, ar3, cnt, gat3);
    k_final<<<1, 256, 0, stream>>>(gat3, x3, dW, db, out);
}

// Round 13
// 806.359 us; speedup vs baseline: 2.0019x; 1.1993x over previous
//
#include <hip/hip_runtime.h>
#include <hip/hip_bf16.h>

#define NN 100000
#define NE 1600000
#define NBN 5000
#define NCOARSE 512
#define NSB 391   // ceil(NN/256) scan blocks
#define NREP 8    // cnt histogram replicas
#define NREP2 32  // deg2/cursor2 replicas (hot-voxel contention split)

__device__ __forceinline__ unsigned f2ord(float f) {
    unsigned u = __float_as_uint(f);
    return (u & 0x80000000u) ? ~u : (u | 0x80000000u);
}
__device__ __forceinline__ float ord2f(unsigned u) {
    u = (u & 0x80000000u) ? (u & 0x7FFFFFFFu) : ~u;
    return __uint_as_float(u);
}
__device__ __forceinline__ float lrelu(float x) { return x > 0.f ? x : 0.01f * x; }

// ---- mark boundary nodes ----
__global__ __launch_bounds__(256) void k_scatter(const int* __restrict__ bn, unsigned char* __restrict__ isb) {
    int i = blockIdx.x * 256 + threadIdx.x;
    if (i < NBN) isb[bn[i]] = 1;
}

// ---- embed ----
__global__ __launch_bounds__(256) void k_embed(const float* __restrict__ nodes, const unsigned char* __restrict__ isb,
                                               const float* __restrict__ dmean, const float* __restrict__ dstd,
                                               const float* __restrict__ eW, const float* __restrict__ eb,
                                               float* __restrict__ x) {
    __shared__ float sW[448];
    __shared__ float sb[64];
    __shared__ float sm[3], sd[3];
    int t = threadIdx.x;
    for (int i = t; i < 448; i += 256) sW[i] = eW[i];
    if (t < 64) sb[t] = eb[t];
    if (t < 3) { sm[t] = dmean[t]; sd[t] = dstd[t]; }
    __syncthreads();
    int lane = t & 63, wv = t >> 6;
    int w = blockIdx.x * 4 + wv, nw = gridDim.x * 4;
    for (int n = w; n < NN; n += nw) {
        float row[7];
#pragma unroll
        for (int k = 0; k < 7; k++) row[k] = nodes[n * 7 + k];
        if (isb[n]) {
#pragma unroll
            for (int k = 0; k < 3; k++) row[3 + k] = (row[3 + k] - sm[k]) / sd[k];
        }
        float acc = sb[lane];
#pragma unroll
        for (int k = 0; k < 7; k++) acc += row[k] * sW[k * 64 + lane];
        x[n * 64 + lane] = acc;
    }
}

// ---- coords min/max ----
__global__ __launch_bounds__(256) void k_minmax(const float* __restrict__ nodes, unsigned* __restrict__ mn_ord,
                                                unsigned* __restrict__ mx_ord) {
    int tid = blockIdx.x * 256 + threadIdx.x;
    int stride = gridDim.x * 256;
    float mn[3] = {INFINITY, INFINITY, INFINITY};
    float mx[3] = {-INFINITY, -INFINITY, -INFINITY};
    for (int n = tid; n < NN; n += stride) {
#pragma unroll
        for (int k = 0; k < 3; k++) {
            float c = nodes[n * 7 + k];
            mn[k] = fminf(mn[k], c);
            mx[k] = fmaxf(mx[k], c);
        }
    }
#pragma unroll
    for (int off = 32; off; off >>= 1) {
#pragma unroll
        for (int k = 0; k < 3; k++) {
            mn[k] = fminf(mn[k], __shfl_down(mn[k], off));
            mx[k] = fmaxf(mx[k], __shfl_down(mx[k], off));
        }
    }
    if ((threadIdx.x & 63) == 0) {
#pragma unroll
        for (int k = 0; k < 3; k++) {
            atomicMin(&mn_ord[k], f2ord(mn[k]));
            atomicMax(&mx_ord[k], f2ord(mx[k]));
        }
    }
}

// ---- voxel block id ----
__global__ __launch_bounds__(256) void k_bid(const float* __restrict__ nodes, const unsigned* __restrict__ mn_ord,
                                             const unsigned* __restrict__ mx_ord, int* __restrict__ bid) {
    int n = blockIdx.x * 256 + threadIdx.x;
    if (n >= NN) return;
    int g[3];
#pragma unroll
    for (int k = 0; k < 3; k++) {
        float mn = ord2f(mn_ord[k]), mx = ord2f(mx_ord[k]);
        float cell = (mx - mn) / 8.0f;
        int gi = (int)floorf((nodes[n * 7 + k] - mn) / cell);
        gi = gi < 0 ? 0 : (gi > 7 ? 7 : gi);
        g[k] = gi;
    }
    bid[n] = g[0] * 64 + g[1] * 8 + g[2];
}

// ---- h = x@W; a_s = h·A[:64]; a_r = h·A[64:] ----
__global__ __launch_bounds__(256) void k_mm(const float* __restrict__ x, const float* __restrict__ W,
                                            const float* __restrict__ A, float* __restrict__ h,
                                            float* __restrict__ as_, float* __restrict__ ar_, int nrow) {
    __shared__ float sW[4096];
    __shared__ float sA[128];
    int t = threadIdx.x;
    for (int i = t; i < 4096; i += 256) sW[i] = W[i];
    if (t < 128) sA[t] = A[t];
    __syncthreads();
    int lane = t & 63, wv = t >> 6;
    int w = blockIdx.x * 4 + wv, nw = gridDim.x * 4;
    for (int n = w; n < nrow; n += nw) {
        const float* xr = x + (size_t)n * 64;
        float acc = 0.f;
#pragma unroll
        for (int k = 0; k < 64; k++) acc += xr[k] * sW[k * 64 + lane];
        h[(size_t)n * 64 + lane] = acc;
        float va = acc * sA[lane], vr = acc * sA[64 + lane];
#pragma unroll
        for (int off = 32; off; off >>= 1) {
            va += __shfl_down(va, off);
            vr += __shfl_down(vr, off);
        }
        if (lane == 0) { as_[n] = va; ar_[n] = vr; }
    }
}

// ---- CSR by receiver: degree histogram ----
__global__ __launch_bounds__(256) void k_deg(const int* __restrict__ re, unsigned* __restrict__ deg) {
    int e = blockIdx.x * 256 + threadIdx.x;
    if (e < NE) atomicAdd(&deg[re[e]], 1u);
}

__global__ __launch_bounds__(256) void k_scan1(const unsigned* __restrict__ deg, unsigned* __restrict__ rowptr,
                                               unsigned* __restrict__ partial) {
    __shared__ unsigned s[256];
    int t = threadIdx.x, i = blockIdx.x * 256 + t;
    unsigned v = (i < NN) ? deg[i] : 0u;
    s[t] = v;
    __syncthreads();
    for (int off = 1; off < 256; off <<= 1) {
        unsigned u = (t >= off) ? s[t - off] : 0u;
        __syncthreads();
        s[t] += u;
        __syncthreads();
    }
    if (i < NN) rowptr[i] = s[t] - v;
    if (t == 255) partial[blockIdx.x] = s[255];
}

__global__ __launch_bounds__(512) void k_scan2(unsigned* __restrict__ partial) {
    __shared__ unsigned s[512];
    int t = threadIdx.x;
    unsigned v = (t < NSB) ? partial[t] : 0u;
    s[t] = v;
    __syncthreads();
    for (int off = 1; off < 512; off <<= 1) {
        unsigned u = (t >= off) ? s[t - off] : 0u;
        __syncthreads();
        s[t] += u;
        __syncthreads();
    }
    if (t < NSB) partial[t] = s[t] - v;
}

__global__ __launch_bounds__(256) void k_scan3(unsigned* __restrict__ rowptr, const unsigned* __restrict__ partial,
                                               unsigned* __restrict__ cursor) {
    int t = threadIdx.x, i = blockIdx.x * 256 + t;
    if (i < NN) {
        unsigned r = rowptr[i] + partial[blockIdx.x];
        rowptr[i] = r;
        cursor[i] = r;
    }
    if (i == 0) rowptr[NN] = NE;
}

// ---- CSR fill: atomicExch store (4B coherence-point write, no 64B line amplification) ----
__global__ __launch_bounds__(256) void k_fill(const int* __restrict__ se, const int* __restrict__ re,
                                              unsigned* __restrict__ cursor, int* __restrict__ csr_s) {
    int e = blockIdx.x * 256 + threadIdx.x;
    if (e >= NE) return;
    unsigned pos = atomicAdd(&cursor[re[e]], 1u);
    atomicExch(&csr_s[pos], se[e]);
}

// ---- fused fine GAT (online softmax, CSR, index prefetch) ----
__global__ __launch_bounds__(256) void k_gat1(const unsigned* __restrict__ rowptr, const int* __restrict__ csr_s,
                                              const float* __restrict__ as_, const float* __restrict__ ar_,
                                              const float* __restrict__ h, float* __restrict__ o_raw) {
    int t = threadIdx.x, lane = t & 63, wv = t >> 6;
    int r = blockIdx.x * 4 + wv;
    int g = lane >> 4, fl = lane & 15;
    int p0 = rowptr[r], p1 = rowptr[r + 1];
    float arj = ar_[r];
    float m = -INFINITY, ss = 0.f;
    float a0 = 0.f, a1 = 0.f, a2 = 0.f, a3 = 0.f;
    int p = p0 + g;
    int s = (p < p1) ? csr_s[p] : 0;
    while (p < p1) {
        int pn = p + 4;
        int sn = (pn < p1) ? csr_s[pn] : 0;
        float sc = lrelu(as_[s] + arj);
        const float4 hv = *(const float4*)(h + (size_t)s * 64 + fl * 4);
        float newm = fmaxf(m, sc);
        float scale = __expf(m - newm);
        float w = __expf(sc - newm);
        ss = ss * scale + w;
        a0 = a0 * scale + w * hv.x;
        a1 = a1 * scale + w * hv.y;
        a2 = a2 * scale + w * hv.z;
        a3 = a3 * scale + w * hv.w;
        m = newm;
        p = pn;
        s = sn;
    }
#pragma unroll
    for (int off = 16; off < 64; off <<= 1) {
        float m2 = __shfl_xor(m, off);
        float ss2 = __shfl_xor(ss, off);
        float b0 = __shfl_xor(a0, off), b1 = __shfl_xor(a1, off);
        float b2 = __shfl_xor(a2, off), b3 = __shfl_xor(a3, off);
        float M = fmaxf(m, m2);
        float e1 = (M == -INFINITY) ? 0.f : __expf(m - M);
        float e2 = (M == -INFINITY) ? 0.f : __expf(m2 - M);
        ss = ss * e1 + ss2 * e2;
        a0 = a0 * e1 + b0 * e2;
        a1 = a1 * e1 + b1 * e2;
        a2 = a2 * e1 + b2 * e2;
        a3 = a3 * e1 + b3 * e2;
        m = M;
    }
    if (g == 0) {
        float inv = ss > 0.f ? 1.f / ss : 0.f;
        float4 v = make_float4(a0 * inv, a1 * inv, a2 * inv, a3 * inv);
        *(float4*)(o_raw + (size_t)r * 64 + fl * 4) = v;
    }
}

// ---- column stats over o_raw (512-block grid) ----
__global__ __launch_bounds__(256) void k_stats2(const float* __restrict__ o_raw,
                                                float* __restrict__ colsum, float* __restrict__ colsq) {
    __shared__ float l1[4][64], l2[4][64];
    int t = threadIdx.x, lane = t & 63, wv = t >> 6;
    int w = blockIdx.x * 4 + wv, nw = gridDim.x * 4;
    float cs = 0.f, cq = 0.f;
    for (int n = w; n < NN; n += nw) {
        float v = o_raw[(size_t)n * 64 + lane];
        cs += v;
        cq += v * v;
    }
    l1[wv][lane] = cs;
    l2[wv][lane] = cq;
    __syncthreads();
    if (wv == 0) {
        float a = l1[0][lane] + l1[1][lane] + l1[2][lane] + l1[3][lane];
        float b = l2[0][lane] + l2[1][lane] + l2[2][lane] + l2[3][lane];
        unsafeAtomicAdd(&colsum[lane], a);
        unsafeAtomicAdd(&colsq[lane], b);
    }
}

__global__ void k_meanvar(const float* __restrict__ colsum, const float* __restrict__ colsq, float* __restrict__ mr) {
    int t = threadIdx.x;
    if (t < 64) {
        float mean = colsum[t] / (float)NN;
        float var = colsq[t] / (float)NN - mean * mean;
        mr[t] = mean;
        mr[64 + t] = rsqrtf(var + 1e-5f);
    }
}

// ---- graphnorm + silu + res1 (pure streaming) ----
__global__ __launch_bounds__(256) void k_apply(const float* __restrict__ o_raw, const float* __restrict__ res1,
                                               const float* __restrict__ gamma, const float* __restrict__ beta,
                                               const float* __restrict__ mr, float* __restrict__ x1) {
    int t = threadIdx.x, lane = t & 63;
    int n = blockIdx.x * 4 + (t >> 6);
    if (n >= NN) return;
    float v = o_raw[(size_t)n * 64 + lane];
    float y = gamma[lane] * (v - mr[lane]) * mr[64 + lane] + beta[lane];
    float s = y / (1.f + __expf(-y));
    x1[(size_t)n * 64 + lane] = s + res1[(size_t)n * 64 + lane];
}

// ---- CSR by bid: 32-replica histogram (hot-voxel contention /32) ----
__global__ __launch_bounds__(256) void k_deg2(const int* __restrict__ bid, unsigned* __restrict__ deg2r) {
    int n = blockIdx.x * 256 + threadIdx.x;
    if (n < NN) atomicAdd(&deg2r[(n & (NREP2 - 1)) * NCOARSE + bid[n]], 1u);
}

// one block, 512 threads: per-voxel totals, exclusive scan, per-replica sub-range cursors
__global__ __launch_bounds__(512) void k_scanb(const unsigned* __restrict__ deg2r, unsigned* __restrict__ rowptr2,
                                               unsigned* __restrict__ cursor2r, unsigned* __restrict__ deg2) {
    __shared__ unsigned s[512];
    int b = threadIdx.x;
    unsigned tot = 0;
    for (int r = 0; r < NREP2; r++) tot += deg2r[r * NCOARSE + b];
    deg2[b] = tot;
    s[b] = tot;
    __syncthreads();
    for (int off = 1; off < 512; off <<= 1) {
        unsigned u = (b >= off) ? s[b - off] : 0u;
        __syncthreads();
        s[b] += u;
        __syncthreads();
    }
    unsigned base = s[b] - tot;   // exclusive
    rowptr2[b] = base;
    if (b == 0) rowptr2[NCOARSE] = NN;
    unsigned run = base;
    for (int r = 0; r < NREP2; r++) {
        cursor2r[r * NCOARSE + b] = run;
        run += deg2r[r * NCOARSE + b];
    }
}

__global__ __launch_bounds__(256) void k_fill2(const int* __restrict__ bid, unsigned* __restrict__ cursor2r,
                                               int* __restrict__ csr_n) {
    int n = blockIdx.x * 256 + threadIdx.x;
    if (n >= NN) return;
    unsigned pos = atomicAdd(&cursor2r[(n & (NREP2 - 1)) * NCOARSE + bid[n]], 1u);
    atomicExch(&csr_n[pos], n);
}

// ---- cnodes accumulate: segmented reduction over bid-sorted csr_n ----
__global__ __launch_bounds__(256) void k_cnacc(const int* __restrict__ csr_n, const int* __restrict__ bid,
                                               const float* __restrict__ x1, float* __restrict__ cnacc) {
    int t = threadIdx.x, lane = t & 63, wv = t >> 6;
    int q0 = (blockIdx.x * 4 + wv) * 64;
    if (q0 >= NN) return;
    int q1 = q0 + 64 < NN ? q0 + 64 : NN;
    int n = csr_n[q0];
    int cur = bid[n];
    float acc = 0.f;
    for (int q = q0; q < q1; q++) {
        int n2 = (q + 1 < q1) ? csr_n[q + 1] : 0;
        int b2 = (q + 1 < q1) ? bid[n2] : -1;
        acc += x1[(size_t)n * 64 + lane];
        if (b2 != cur) {
            unsafeAtomicAdd(&cnacc[cur * 64 + lane], acc);
            acc = 0.f;
            cur = b2;
        }
        n = n2;
    }
}

// ---- cnodes scale ----
__global__ __launch_bounds__(256) void k_cnscale(const float* __restrict__ cnacc, const unsigned* __restrict__ deg2,
                                                 float* __restrict__ x2) {
    int t = threadIdx.x, lane = t & 63;
    int b = blockIdx.x * 4 + (t >> 6);
    if (b >= NCOARSE) return;
    x2[b * 64 + lane] = cnacc[b * 64 + lane] / sqrtf((float)deg2[b] + 1e-10f);
}

// ---- coarse edge-count: 8-replica histogram ----
__global__ __launch_bounds__(256) void k_cnt(const int* __restrict__ se, const int* __restrict__ re,
                                             const int* __restrict__ bid, unsigned* __restrict__ cntr) {
    int e = blockIdx.x * 256 + threadIdx.x;
    if (e >= NE) return;
    int rep = e & (NREP - 1);
    atomicAdd(&cntr[(size_t)rep * NCOARSE * NCOARSE + bid[re[e]] * NCOARSE + bid[se[e]]], 1u);
}

__global__ __launch_bounds__(256) void k_cntmerge(const unsigned* __restrict__ cntr, unsigned* __restrict__ cnt) {
    int i = blockIdx.x * 256 + threadIdx.x;
    unsigned s = 0;
#pragma unroll
    for (int r = 0; r < NREP; r++) s += cntr[(size_t)r * NCOARSE * NCOARSE + i];
    cnt[i] = s;
}

// ---- dense coarse GAT: block per receiver j ----
__global__ __launch_bounds__(256) void k_cgat(const float* __restrict__ h, const float* __restrict__ as_,
                                              const float* __restrict__ ar_, const unsigned* __restrict__ cnt,
                                              float* __restrict__ g) {
    __shared__ float red[256];
    __shared__ float sw[NCOARSE];
    __shared__ float acc_s[4][64];
    int t = threadIdx.x, lane = t & 63, wv = t >> 6;
    int j = blockIdx.x;
    float arj = ar_[j];
    unsigned c0 = cnt[j * NCOARSE + t], c1 = cnt[j * NCOARSE + t + 256];
    float s0 = lrelu(as_[t] + arj), s1 = lrelu(as_[t + 256] + arj);
    float v0 = c0 ? s0 : -INFINITY, v1 = c1 ? s1 : -INFINITY;
    red[t] = fmaxf(v0, v1);
    __syncthreads();
    for (int off = 128; off; off >>= 1) {
        if (t < off) red[t] = fmaxf(red[t], red[t + off]);
        __syncthreads();
    }
    float m = red[0];
    __syncthreads();
    float w0 = c0 ? (float)c0 * __expf(s0 - m) : 0.f;
    float w1 = c1 ? (float)c1 * __expf(s1 - m) : 0.f;
    sw[t] = w0;
    sw[t + 256] = w1;
    red[t] = w0 + w1;
    __syncthreads();
    for (int off = 128; off; off >>= 1) {
        if (t < off) red[t] += red[t + off];
        __syncthreads();
    }
    float ss = red[0];
    float acc = 0.f;
    int i0 = wv * 128;
#pragma unroll 4
    for (int i = i0; i < i0 + 128; i++) acc += sw[i] * h[i * 64 + lane];
    acc_s[wv][lane] = acc;
    __syncthreads();
    if (wv == 0) {
        float tot = acc_s[0][lane] + acc_s[1][lane] + acc_s[2][lane] + acc_s[3][lane];
        g[j * 64 + lane] = ss > 0.f ? tot / ss : 0.f;
    }
}

// ---- coarse graphnorm + silu + residual ----
__global__ __launch_bounds__(64) void k_cnorm(const float* __restrict__ gin, const float* __restrict__ gamma,
                                              const float* __restrict__ beta, const float* __restrict__ res,
                                              float* __restrict__ xout) {
    int f = blockIdx.x, lane = threadIdx.x;
    float v[8];
    float s = 0.f, q = 0.f;
#pragma unroll
    for (int k = 0; k < 8; k++) {
        v[k] = gin[(lane + 64 * k) * 64 + f];
        s += v[k];
        q += v[k] * v[k];
    }
#pragma unroll
    for (int off = 32; off; off >>= 1) {
        s += __shfl_down(s, off);
        q += __shfl_down(q, off);
    }
    s = __shfl(s, 0);
    q = __shfl(q, 0);
    float mean = s / 512.f, var = q / 512.f - mean * mean, rstd = rsqrtf(var + 1e-5f);
    float gf = gamma[f], bf = beta[f];
#pragma unroll
    for (int k = 0; k < 8; k++) {
        float y = gf * (v[k] - mean) * rstd + bf;
        float si = y / (1.f + __expf(-y));
        int idx = (lane + 64 * k) * 64 + f;
        xout[idx] = si + res[idx];
    }
}

// ---- final reduction ----
__global__ __launch_bounds__(256) void k_final(const float* __restrict__ g3, const float* __restrict__ x3,
                                               const float* __restrict__ dW, const float* __restrict__ db,
                                               float* __restrict__ out) {
    __shared__ float l[4];
    int t = threadIdx.x;
    float p = 0.f;
    for (int idx = t; idx < NCOARSE * 64; idx += 256) p += (g3[idx] + x3[idx]) * dW[idx & 63];
#pragma unroll
    for (int off = 32; off; off >>= 1) p += __shfl_down(p, off);
    if ((t & 63) == 0) l[t >> 6] = p;
    __syncthreads();
    if (t == 0) out[0] = l[0] + l[1] + l[2] + l[3] + db[0];
}

extern "C" void kernel_launch(void* const* d_in, const int* in_sizes, int n_in,
                              void* d_out, int out_size, void* d_ws, size_t ws_size,
                              hipStream_t stream) {
    const float* nodes = (const float*)d_in[0];
    const int* senders = (const int*)d_in[1];
    const int* receivers = (const int*)d_in[2];
    const int* bnodes = (const int*)d_in[3];
    const float* dmean = (const float*)d_in[4];
    const float* dstd = (const float*)d_in[5];
    const float* eW = (const float*)d_in[6];
    const float* eb = (const float*)d_in[7];
    const float* W1 = (const float*)d_in[8];
    const float* A1 = (const float*)d_in[9];
    const float* gamma1 = (const float*)d_in[10];
    const float* beta1 = (const float*)d_in[11];
    const float* W2 = (const float*)d_in[12];
    const float* A2 = (const float*)d_in[13];
    const float* gamma2 = (const float*)d_in[14];
    const float* beta2 = (const float*)d_in[15];
    const float* W3 = (const float*)d_in[16];
    const float* A3 = (const float*)d_in[17];
    const float* dW = (const float*)d_in[18];
    const float* db = (const float*)d_in[19];
    float* out = (float*)d_out;

    char* p = (char*)d_ws;
    auto alloc = [&](size_t b) { char* r = p; p += (b + 255) & ~(size_t)255; return r; };
    float* x_emb = (float*)alloc((size_t)NN * 64 * 4);   // res1
    float* h1 = (float*)alloc((size_t)NN * 64 * 4);      // reused as x1 after gat1
    float* o_raw = (float*)alloc((size_t)NN * 64 * 4);
    float* as1 = (float*)alloc(NN * 4);
    float* ar1 = (float*)alloc(NN * 4);
    int* bid = (int*)alloc(NN * 4);
    unsigned char* isb = (unsigned char*)alloc(NN);
    float* colsum = (float*)alloc(64 * 4);
    float* colsq = (float*)alloc(64 * 4);
    float* mr = (float*)alloc(128 * 4);
    unsigned* mn_ord = (unsigned*)alloc(3 * 4);
    unsigned* mx_ord = (unsigned*)alloc(3 * 4);
    unsigned* cnt = (unsigned*)alloc((size_t)NCOARSE * NCOARSE * 4);
    unsigned* cntr = (unsigned*)alloc((size_t)NREP * NCOARSE * NCOARSE * 4);
    float* cnacc = (float*)alloc(NCOARSE * 64 * 4);
    float* x2 = (float*)alloc(NCOARSE * 64 * 4);   // res2
    float* h2 = (float*)alloc(NCOARSE * 64 * 4);
    float* as2 = (float*)alloc(NCOARSE * 4);
    float* ar2 = (float*)alloc(NCOARSE * 4);
    float* gat2 = (float*)alloc(NCOARSE * 64 * 4);
    float* x3 = (float*)alloc(NCOARSE * 64 * 4);   // res3
    float* h3 = (float*)alloc(NCOARSE * 64 * 4);
    float* as3 = (float*)alloc(NCOARSE * 4);
    float* ar3 = (float*)alloc(NCOARSE * 4);
    float* gat3 = (float*)alloc(NCOARSE * 64 * 4);
    unsigned* deg = (unsigned*)alloc(NN * 4);
    unsigned* rowptr = (unsigned*)alloc((NN + 1) * 4);
    unsigned* cursor = (unsigned*)alloc(NN * 4);
    unsigned* partial = (unsigned*)alloc(512 * 4);
    int* csr_s = (int*)alloc((size_t)NE * 4);
    unsigned* deg2r = (unsigned*)alloc((size_t)NREP2 * NCOARSE * 4);
    unsigned* deg2 = (unsigned*)alloc(NCOARSE * 4);
    unsigned* rowptr2 = (unsigned*)alloc((NCOARSE + 1) * 4);
    unsigned* cursor2r = (unsigned*)alloc((size_t)NREP2 * NCOARSE * 4);
    int* csr_n = (int*)alloc(NN * 4);

    hipMemsetAsync(isb, 0, NN, stream);
    hipMemsetAsync(colsum, 0, 64 * 4, stream);
    hipMemsetAsync(colsq, 0, 64 * 4, stream);
    hipMemsetAsync(mn_ord, 0xFF, 12, stream);
    hipMemsetAsync(mx_ord, 0, 12, stream);
    hipMemsetAsync(cntr, 0, (size_t)NREP * NCOARSE * NCOARSE * 4, stream);
    hipMemsetAsync(cnacc, 0, NCOARSE * 64 * 4, stream);
    hipMemsetAsync(deg, 0, NN * 4, stream);
    hipMemsetAsync(deg2r, 0, (size_t)NREP2 * NCOARSE * 4, stream);

    k_scatter<<<(NBN + 255) / 256, 256, 0, stream>>>(bnodes, isb);
    k_embed<<<2048, 256, 0, stream>>>(nodes, isb, dmean, dstd, eW, eb, x_emb);
    k_minmax<<<512, 256, 0, stream>>>(nodes, mn_ord, mx_ord);
    k_bid<<<(NN + 255) / 256, 256, 0, stream>>>(nodes, mn_ord, mx_ord, bid);
    k_deg<<<(NE + 255) / 256, 256, 0, stream>>>(receivers, deg);
    k_scan1<<<NSB, 256, 0, stream>>>(deg, rowptr, partial);
    k_scan2<<<1, 512, 0, stream>>>(partial);
    k_scan3<<<NSB, 256, 0, stream>>>(rowptr, partial, cursor);
    k_fill<<<(NE + 255) / 256, 256, 0, stream>>>(senders, receivers, cursor, csr_s);
    k_deg2<<<(NN + 255) / 256, 256, 0, stream>>>(bid, deg2r);
    k_scanb<<<1, 512, 0, stream>>>(deg2r, rowptr2, cursor2r, deg2);
    k_fill2<<<(NN + 255) / 256, 256, 0, stream>>>(bid, cursor2r, csr_n);
    k_cnt<<<(NE + 255) / 256, 256, 0, stream>>>(senders, receivers, bid, cntr);
    k_cntmerge<<<NCOARSE * NCOARSE / 256, 256, 0, stream>>>(cntr, cnt);
    k_mm<<<2048, 256, 0, stream>>>(x_emb, W1, A1, h1, as1, ar1, NN);
    k_gat1<<<NN / 4, 256, 0, stream>>>(rowptr, csr_s, as1, ar1, h1, o_raw);
    k_stats2<<<512, 256, 0, stream>>>(o_raw, colsum, colsq);
    k_meanvar<<<1, 64, 0, stream>>>(colsum, colsq, mr);
    k_apply<<<NN / 4, 256, 0, stream>>>(o_raw, x_emb, gamma1, beta1, mr, h1);
    k_cnacc<<<NSB, 256, 0, stream>>>(csr_n, bid, h1, cnacc);
    k_cnscale<<<NCOARSE / 4, 256, 0, stream>>>(cnacc, deg2, x2);
    k_mm<<<NCOARSE / 4, 256, 0, stream>>>(x2, W2, A2, h2, as2, ar2, NCOARSE);
    k_cgat<<<NCOARSE, 256, 0, stream>>>(h2, as2, ar2, cnt, gat2);
    k_cnorm<<<64, 64, 0, stream>>>(gat2, gamma2, beta2, x2, x3);
    k_mm<<<NCOARSE / 4, 256, 0, stream>>>(x3, W3, A3, h3, as3, ar3, NCOARSE);
    k_cgat<<<NCOARSE, 256, 0, stream>>>(h3, as3, ar3, cnt, gat3);
    k_final<<<1, 256, 0, stream>>>(gat3, x3, dW, db, out);
}

// Round 14
// 740.162 us; speedup vs baseline: 2.1809x; 1.0894x over previous
//
#include <hip/hip_runtime.h>
#include <hip/hip_bf16.h>

#define NN 100000
#define NE 1600000
#define NBN 5000
#define NCOARSE 512
#define NSB 391   // ceil(NN/256) scan blocks
#define NREP 8    // cnt histogram replicas
#define NREP2 32  // deg2/cursor2 replicas
#define NBUCK 196 // ceil(NN/512) receiver buckets
#define P1TILE 8192

__device__ __forceinline__ unsigned f2ord(float f) {
    unsigned u = __float_as_uint(f);
    return (u & 0x80000000u) ? ~u : (u | 0x80000000u);
}
__device__ __forceinline__ float ord2f(unsigned u) {
    u = (u & 0x80000000u) ? (u & 0x7FFFFFFFu) : ~u;
    return __uint_as_float(u);
}
__device__ __forceinline__ float lrelu(float x) { return x > 0.f ? x : 0.01f * x; }

// ---- mark boundary nodes ----
__global__ __launch_bounds__(256) void k_scatter(const int* __restrict__ bn, unsigned char* __restrict__ isb) {
    int i = blockIdx.x * 256 + threadIdx.x;
    if (i < NBN) isb[bn[i]] = 1;
}

// ---- embed ----
__global__ __launch_bounds__(256) void k_embed(const float* __restrict__ nodes, const unsigned char* __restrict__ isb,
                                               const float* __restrict__ dmean, const float* __restrict__ dstd,
                                               const float* __restrict__ eW, const float* __restrict__ eb,
                                               float* __restrict__ x) {
    __shared__ float sW[448];
    __shared__ float sb[64];
    __shared__ float sm[3], sd[3];
    int t = threadIdx.x;
    for (int i = t; i < 448; i += 256) sW[i] = eW[i];
    if (t < 64) sb[t] = eb[t];
    if (t < 3) { sm[t] = dmean[t]; sd[t] = dstd[t]; }
    __syncthreads();
    int lane = t & 63, wv = t >> 6;
    int w = blockIdx.x * 4 + wv, nw = gridDim.x * 4;
    for (int n = w; n < NN; n += nw) {
        float row[7];
#pragma unroll
        for (int k = 0; k < 7; k++) row[k] = nodes[n * 7 + k];
        if (isb[n]) {
#pragma unroll
            for (int k = 0; k < 3; k++) row[3 + k] = (row[3 + k] - sm[k]) / sd[k];
        }
        float acc = sb[lane];
#pragma unroll
        for (int k = 0; k < 7; k++) acc += row[k] * sW[k * 64 + lane];
        x[n * 64 + lane] = acc;
    }
}

// ---- coords min/max ----
__global__ __launch_bounds__(256) void k_minmax(const float* __restrict__ nodes, unsigned* __restrict__ mn_ord,
                                                unsigned* __restrict__ mx_ord) {
    int tid = blockIdx.x * 256 + threadIdx.x;
    int stride = gridDim.x * 256;
    float mn[3] = {INFINITY, INFINITY, INFINITY};
    float mx[3] = {-INFINITY, -INFINITY, -INFINITY};
    for (int n = tid; n < NN; n += stride) {
#pragma unroll
        for (int k = 0; k < 3; k++) {
            float c = nodes[n * 7 + k];
            mn[k] = fminf(mn[k], c);
            mx[k] = fmaxf(mx[k], c);
        }
    }
#pragma unroll
    for (int off = 32; off; off >>= 1) {
#pragma unroll
        for (int k = 0; k < 3; k++) {
            mn[k] = fminf(mn[k], __shfl_down(mn[k], off));
            mx[k] = fmaxf(mx[k], __shfl_down(mx[k], off));
        }
    }
    if ((threadIdx.x & 63) == 0) {
#pragma unroll
        for (int k = 0; k < 3; k++) {
            atomicMin(&mn_ord[k], f2ord(mn[k]));
            atomicMax(&mx_ord[k], f2ord(mx[k]));
        }
    }
}

// ---- voxel block id ----
__global__ __launch_bounds__(256) void k_bid(const float* __restrict__ nodes, const unsigned* __restrict__ mn_ord,
                                             const unsigned* __restrict__ mx_ord, int* __restrict__ bid) {
    int n = blockIdx.x * 256 + threadIdx.x;
    if (n >= NN) return;
    int g[3];
#pragma unroll
    for (int k = 0; k < 3; k++) {
        float mn = ord2f(mn_ord[k]), mx = ord2f(mx_ord[k]);
        float cell = (mx - mn) / 8.0f;
        int gi = (int)floorf((nodes[n * 7 + k] - mn) / cell);
        gi = gi < 0 ? 0 : (gi > 7 ? 7 : gi);
        g[k] = gi;
    }
    bid[n] = g[0] * 64 + g[1] * 8 + g[2];
}

// ---- h = x@W; a_s = h·A[:64]; a_r = h·A[64:] ----
__global__ __launch_bounds__(256) void k_mm(const float* __restrict__ x, const float* __restrict__ W,
                                            const float* __restrict__ A, float* __restrict__ h,
                                            float* __restrict__ as_, float* __restrict__ ar_, int nrow) {
    __shared__ float sW[4096];
    __shared__ float sA[128];
    int t = threadIdx.x;
    for (int i = t; i < 4096; i += 256) sW[i] = W[i];
    if (t < 128) sA[t] = A[t];
    __syncthreads();
    int lane = t & 63, wv = t >> 6;
    int w = blockIdx.x * 4 + wv, nw = gridDim.x * 4;
    for (int n = w; n < nrow; n += nw) {
        const float* xr = x + (size_t)n * 64;
        float acc = 0.f;
#pragma unroll
        for (int k = 0; k < 64; k++) acc += xr[k] * sW[k * 64 + lane];
        h[(size_t)n * 64 + lane] = acc;
        float va = acc * sA[lane], vr = acc * sA[64 + lane];
#pragma unroll
        for (int off = 32; off; off >>= 1) {
            va += __shfl_down(va, off);
            vr += __shfl_down(vr, off);
        }
        if (lane == 0) { as_[n] = va; ar_[n] = vr; }
    }
}

// ---- CSR by receiver: degree histogram + scan ----
__global__ __launch_bounds__(256) void k_deg(const int* __restrict__ re, unsigned* __restrict__ deg) {
    int e = blockIdx.x * 256 + threadIdx.x;
    if (e < NE) atomicAdd(&deg[re[e]], 1u);
}

__global__ __launch_bounds__(256) void k_scan1(const unsigned* __restrict__ deg, unsigned* __restrict__ rowptr,
                                               unsigned* __restrict__ partial) {
    __shared__ unsigned s[256];
    int t = threadIdx.x, i = blockIdx.x * 256 + t;
    unsigned v = (i < NN) ? deg[i] : 0u;
    s[t] = v;
    __syncthreads();
    for (int off = 1; off < 256; off <<= 1) {
        unsigned u = (t >= off) ? s[t - off] : 0u;
        __syncthreads();
        s[t] += u;
        __syncthreads();
    }
    if (i < NN) rowptr[i] = s[t] - v;
    if (t == 255) partial[blockIdx.x] = s[255];
}

__global__ __launch_bounds__(512) void k_scan2(unsigned* __restrict__ partial) {
    __shared__ unsigned s[512];
    int t = threadIdx.x;
    unsigned v = (t < NSB) ? partial[t] : 0u;
    s[t] = v;
    __syncthreads();
    for (int off = 1; off < 512; off <<= 1) {
        unsigned u = (t >= off) ? s[t - off] : 0u;
        __syncthreads();
        s[t] += u;
        __syncthreads();
    }
    if (t < NSB) partial[t] = s[t] - v;
}

__global__ __launch_bounds__(256) void k_scan3(unsigned* __restrict__ rowptr, const unsigned* __restrict__ partial) {
    int t = threadIdx.x, i = blockIdx.x * 256 + t;
    if (i < NN) rowptr[i] += partial[blockIdx.x];
    if (i == 0) rowptr[NN] = NE;
}

// ---- bucket cursors: gcur[b] = rowptr[b<<9] (bucket regions == rowptr layout) ----
__global__ void k_gcinit(const unsigned* __restrict__ rowptr, unsigned* __restrict__ gcur) {
    int b = threadIdx.x;
    if (b < NBUCK) gcur[b] = rowptr[b << 9];
}

// ---- pass 1: bucket (se,re) pairs by re>>9 with per-tile reservation (locality-preserving) ----
__global__ __launch_bounds__(256) void k_pass1(const int* __restrict__ se, const int* __restrict__ re,
                                               unsigned* __restrict__ gcur, int* __restrict__ pairSe,
                                               int* __restrict__ pairRe) {
    __shared__ unsigned hist[NBUCK], cur[NBUCK], gbase[NBUCK];
    int t = threadIdx.x;
    int e0 = blockIdx.x * P1TILE;
    for (int i = t; i < NBUCK; i += 256) { hist[i] = 0; cur[i] = 0; }
    __syncthreads();
    for (int i = t; i < P1TILE; i += 256) {
        int e = e0 + i;
        if (e < NE) atomicAdd(&hist[re[e] >> 9], 1u);
    }
    __syncthreads();
    for (int i = t; i < NBUCK; i += 256) gbase[i] = atomicAdd(&gcur[i], hist[i]);
    __syncthreads();
    for (int i = t; i < P1TILE; i += 256) {
        int e = e0 + i;
        if (e < NE) {
            int r = re[e];
            int b = r >> 9;
            unsigned j = atomicAdd(&cur[b], 1u);
            unsigned pos = gbase[b] + j;
            pairSe[pos] = se[e];
            pairRe[pos] = r;
        }
    }
}

// ---- pass 2: within-bucket scatter to csr_s (writes confined to ~32KB region per block) ----
__global__ __launch_bounds__(256) void k_pass2(const unsigned* __restrict__ rowptr, const int* __restrict__ pairSe,
                                               const int* __restrict__ pairRe, int* __restrict__ csr_s) {
    __shared__ unsigned cur[512];
    int t = threadIdx.x;
    int r0 = blockIdx.x << 9;
    for (int i = t; i < 512; i += 256) {
        int r = r0 + i;
        cur[i] = (r < NN) ? rowptr[r] : 0u;
    }
    __syncthreads();
    unsigned p0 = rowptr[r0];
    int rend = r0 + 512 < NN ? r0 + 512 : NN;
    unsigned p1 = rowptr[rend];
    for (unsigned p = p0 + t; p < p1; p += 256) {
        int r = pairRe[p];
        unsigned pos = atomicAdd(&cur[r - r0], 1u);
        csr_s[pos] = pairSe[p];
    }
}

// ---- fused fine GAT (online softmax, CSR, index prefetch) ----
__global__ __launch_bounds__(256) void k_gat1(const unsigned* __restrict__ rowptr, const int* __restrict__ csr_s,
                                              const float* __restrict__ as_, const float* __restrict__ ar_,
                                              const float* __restrict__ h, float* __restrict__ o_raw) {
    int t = threadIdx.x, lane = t & 63, wv = t >> 6;
    int r = blockIdx.x * 4 + wv;
    int g = lane >> 4, fl = lane & 15;
    int p0 = rowptr[r], p1 = rowptr[r + 1];
    float arj = ar_[r];
    float m = -INFINITY, ss = 0.f;
    float a0 = 0.f, a1 = 0.f, a2 = 0.f, a3 = 0.f;
    int p = p0 + g;
    int s = (p < p1) ? csr_s[p] : 0;
    while (p < p1) {
        int pn = p + 4;
        int sn = (pn < p1) ? csr_s[pn] : 0;
        float sc = lrelu(as_[s] + arj);
        const float4 hv = *(const float4*)(h + (size_t)s * 64 + fl * 4);
        float newm = fmaxf(m, sc);
        float scale = __expf(m - newm);
        float w = __expf(sc - newm);
        ss = ss * scale + w;
        a0 = a0 * scale + w * hv.x;
        a1 = a1 * scale + w * hv.y;
        a2 = a2 * scale + w * hv.z;
        a3 = a3 * scale + w * hv.w;
        m = newm;
        p = pn;
        s = sn;
    }
#pragma unroll
    for (int off = 16; off < 64; off <<= 1) {
        float m2 = __shfl_xor(m, off);
        float ss2 = __shfl_xor(ss, off);
        float b0 = __shfl_xor(a0, off), b1 = __shfl_xor(a1, off);
        float b2 = __shfl_xor(a2, off), b3 = __shfl_xor(a3, off);
        float M = fmaxf(m, m2);
        float e1 = (M == -INFINITY) ? 0.f : __expf(m - M);
        float e2 = (M == -INFINITY) ? 0.f : __expf(m2 - M);
        ss = ss * e1 + ss2 * e2;
        a0 = a0 * e1 + b0 * e2;
        a1 = a1 * e1 + b1 * e2;
        a2 = a2 * e1 + b2 * e2;
        a3 = a3 * e1 + b3 * e2;
        m = M;
    }
    if (g == 0) {
        float inv = ss > 0.f ? 1.f / ss : 0.f;
        float4 v = make_float4(a0 * inv, a1 * inv, a2 * inv, a3 * inv);
        *(float4*)(o_raw + (size_t)r * 64 + fl * 4) = v;
    }
}

// ---- column stats over o_raw (512-block grid) ----
__global__ __launch_bounds__(256) void k_stats2(const float* __restrict__ o_raw,
                                                float* __restrict__ colsum, float* __restrict__ colsq) {
    __shared__ float l1[4][64], l2[4][64];
    int t = threadIdx.x, lane = t & 63, wv = t >> 6;
    int w = blockIdx.x * 4 + wv, nw = gridDim.x * 4;
    float cs = 0.f, cq = 0.f;
    for (int n = w; n < NN; n += nw) {
        float v = o_raw[(size_t)n * 64 + lane];
        cs += v;
        cq += v * v;
    }
    l1[wv][lane] = cs;
    l2[wv][lane] = cq;
    __syncthreads();
    if (wv == 0) {
        float a = l1[0][lane] + l1[1][lane] + l1[2][lane] + l1[3][lane];
        float b = l2[0][lane] + l2[1][lane] + l2[2][lane] + l2[3][lane];
        unsafeAtomicAdd(&colsum[lane], a);
        unsafeAtomicAdd(&colsq[lane], b);
    }
}

__global__ void k_meanvar(const float* __restrict__ colsum, const float* __restrict__ colsq, float* __restrict__ mr) {
    int t = threadIdx.x;
    if (t < 64) {
        float mean = colsum[t] / (float)NN;
        float var = colsq[t] / (float)NN - mean * mean;
        mr[t] = mean;
        mr[64 + t] = rsqrtf(var + 1e-5f);
    }
}

// ---- graphnorm + silu + res1 (pure streaming) ----
__global__ __launch_bounds__(256) void k_apply(const float* __restrict__ o_raw, const float* __restrict__ res1,
                                               const float* __restrict__ gamma, const float* __restrict__ beta,
                                               const float* __restrict__ mr, float* __restrict__ x1) {
    int t = threadIdx.x, lane = t & 63;
    int n = blockIdx.x * 4 + (t >> 6);
    if (n >= NN) return;
    float v = o_raw[(size_t)n * 64 + lane];
    float y = gamma[lane] * (v - mr[lane]) * mr[64 + lane] + beta[lane];
    float s = y / (1.f + __expf(-y));
    x1[(size_t)n * 64 + lane] = s + res1[(size_t)n * 64 + lane];
}

// ---- CSR by bid: 32-replica histogram ----
__global__ __launch_bounds__(256) void k_deg2(const int* __restrict__ bid, unsigned* __restrict__ deg2r) {
    int n = blockIdx.x * 256 + threadIdx.x;
    if (n < NN) atomicAdd(&deg2r[(n & (NREP2 - 1)) * NCOARSE + bid[n]], 1u);
}

__global__ __launch_bounds__(512) void k_scanb(const unsigned* __restrict__ deg2r, unsigned* __restrict__ rowptr2,
                                               unsigned* __restrict__ cursor2r, unsigned* __restrict__ deg2) {
    __shared__ unsigned s[512];
    int b = threadIdx.x;
    unsigned tot = 0;
    for (int r = 0; r < NREP2; r++) tot += deg2r[r * NCOARSE + b];
    deg2[b] = tot;
    s[b] = tot;
    __syncthreads();
    for (int off = 1; off < 512; off <<= 1) {
        unsigned u = (b >= off) ? s[b - off] : 0u;
        __syncthreads();
        s[b] += u;
        __syncthreads();
    }
    unsigned base = s[b] - tot;
    rowptr2[b] = base;
    if (b == 0) rowptr2[NCOARSE] = NN;
    unsigned run = base;
    for (int r = 0; r < NREP2; r++) {
        cursor2r[r * NCOARSE + b] = run;
        run += deg2r[r * NCOARSE + b];
    }
}

__global__ __launch_bounds__(256) void k_fill2(const int* __restrict__ bid, unsigned* __restrict__ cursor2r,
                                               int* __restrict__ csr_n) {
    int n = blockIdx.x * 256 + threadIdx.x;
    if (n >= NN) return;
    unsigned pos = atomicAdd(&cursor2r[(n & (NREP2 - 1)) * NCOARSE + bid[n]], 1u);
    csr_n[pos] = n;
}

// ---- cnodes accumulate: segmented reduction over bid-sorted csr_n ----
__global__ __launch_bounds__(256) void k_cnacc(const int* __restrict__ csr_n, const int* __restrict__ bid,
                                               const float* __restrict__ x1, float* __restrict__ cnacc) {
    int t = threadIdx.x, lane = t & 63, wv = t >> 6;
    int q0 = (blockIdx.x * 4 + wv) * 64;
    if (q0 >= NN) return;
    int q1 = q0 + 64 < NN ? q0 + 64 : NN;
    int n = csr_n[q0];
    int cur = bid[n];
    float acc = 0.f;
    for (int q = q0; q < q1; q++) {
        int n2 = (q + 1 < q1) ? csr_n[q + 1] : 0;
        int b2 = (q + 1 < q1) ? bid[n2] : -1;
        acc += x1[(size_t)n * 64 + lane];
        if (b2 != cur) {
            unsafeAtomicAdd(&cnacc[cur * 64 + lane], acc);
            acc = 0.f;
            cur = b2;
        }
        n = n2;
    }
}

// ---- cnodes scale ----
__global__ __launch_bounds__(256) void k_cnscale(const float* __restrict__ cnacc, const unsigned* __restrict__ deg2,
                                                 float* __restrict__ x2) {
    int t = threadIdx.x, lane = t & 63;
    int b = blockIdx.x * 4 + (t >> 6);
    if (b >= NCOARSE) return;
    x2[b * 64 + lane] = cnacc[b * 64 + lane] / sqrtf((float)deg2[b] + 1e-10f);
}

// ---- coarse edge-count: 8-replica histogram ----
__global__ __launch_bounds__(256) void k_cnt(const int* __restrict__ se, const int* __restrict__ re,
                                             const int* __restrict__ bid, unsigned* __restrict__ cntr) {
    int e = blockIdx.x * 256 + threadIdx.x;
    if (e >= NE) return;
    int rep = e & (NREP - 1);
    atomicAdd(&cntr[(size_t)rep * NCOARSE * NCOARSE + bid[re[e]] * NCOARSE + bid[se[e]]], 1u);
}

__global__ __launch_bounds__(256) void k_cntmerge(const unsigned* __restrict__ cntr, unsigned* __restrict__ cnt) {
    int i = blockIdx.x * 256 + threadIdx.x;
    unsigned s = 0;
#pragma unroll
    for (int r = 0; r < NREP; r++) s += cntr[(size_t)r * NCOARSE * NCOARSE + i];
    cnt[i] = s;
}

// ---- dense coarse GAT: block per receiver j ----
__global__ __launch_bounds__(256) void k_cgat(const float* __restrict__ h, const float* __restrict__ as_,
                                              const float* __restrict__ ar_, const unsigned* __restrict__ cnt,
                                              float* __restrict__ g) {
    __shared__ float red[256];
    __shared__ float sw[NCOARSE];
    __shared__ float acc_s[4][64];
    int t = threadIdx.x, lane = t & 63, wv = t >> 6;
    int j = blockIdx.x;
    float arj = ar_[j];
    unsigned c0 = cnt[j * NCOARSE + t], c1 = cnt[j * NCOARSE + t + 256];
    float s0 = lrelu(as_[t] + arj), s1 = lrelu(as_[t + 256] + arj);
    float v0 = c0 ? s0 : -INFINITY, v1 = c1 ? s1 : -INFINITY;
    red[t] = fmaxf(v0, v1);
    __syncthreads();
    for (int off = 128; off; off >>= 1) {
        if (t < off) red[t] = fmaxf(red[t], red[t + off]);
        __syncthreads();
    }
    float m = red[0];
    __syncthreads();
    float w0 = c0 ? (float)c0 * __expf(s0 - m) : 0.f;
    float w1 = c1 ? (float)c1 * __expf(s1 - m) : 0.f;
    sw[t] = w0;
    sw[t + 256] = w1;
    red[t] = w0 + w1;
    __syncthreads();
    for (int off = 128; off; off >>= 1) {
        if (t < off) red[t] += red[t + off];
        __syncthreads();
    }
    float ss = red[0];
    float acc = 0.f;
    int i0 = wv * 128;
#pragma unroll 4
    for (int i = i0; i < i0 + 128; i++) acc += sw[i] * h[i * 64 + lane];
    acc_s[wv][lane] = acc;
    __syncthreads();
    if (wv == 0) {
        float tot = acc_s[0][lane] + acc_s[1][lane] + acc_s[2][lane] + acc_s[3][lane];
        g[j * 64 + lane] = ss > 0.f ? tot / ss : 0.f;
    }
}

// ---- coarse graphnorm + silu + residual ----
__global__ __launch_bounds__(64) void k_cnorm(const float* __restrict__ gin, const float* __restrict__ gamma,
                                              const float* __restrict__ beta, const float* __restrict__ res,
                                              float* __restrict__ xout) {
    int f = blockIdx.x, lane = threadIdx.x;
    float v[8];
    float s = 0.f, q = 0.f;
#pragma unroll
    for (int k = 0; k < 8; k++) {
        v[k] = gin[(lane + 64 * k) * 64 + f];
        s += v[k];
        q += v[k] * v[k];
    }
#pragma unroll
    for (int off = 32; off; off >>= 1) {
        s += __shfl_down(s, off);
        q += __shfl_down(q, off);
    }
    s = __shfl(s, 0);
    q = __shfl(q, 0);
    float mean = s / 512.f, var = q / 512.f - mean * mean, rstd = rsqrtf(var + 1e-5f);
    float gf = gamma[f], bf = beta[f];
#pragma unroll
    for (int k = 0; k < 8; k++) {
        float y = gf * (v[k] - mean) * rstd + bf;
        float si = y / (1.f + __expf(-y));
        int idx = (lane + 64 * k) * 64 + f;
        xout[idx] = si + res[idx];
    }
}

// ---- final reduction ----
__global__ __launch_bounds__(256) void k_final(const float* __restrict__ g3, const float* __restrict__ x3,
                                               const float* __restrict__ dW, const float* __restrict__ db,
                                               float* __restrict__ out) {
    __shared__ float l[4];
    int t = threadIdx.x;
    float p = 0.f;
    for (int idx = t; idx < NCOARSE * 64; idx += 256) p += (g3[idx] + x3[idx]) * dW[idx & 63];
#pragma unroll
    for (int off = 32; off; off >>= 1) p += __shfl_down(p, off);
    if ((t & 63) == 0) l[t >> 6] = p;
    __syncthreads();
    if (t == 0) out[0] = l[0] + l[1] + l[2] + l[3] + db[0];
}

extern "C" void kernel_launch(void* const* d_in, const int* in_sizes, int n_in,
                              void* d_out, int out_size, void* d_ws, size_t ws_size,
                              hipStream_t stream) {
    const float* nodes = (const float*)d_in[0];
    const int* senders = (const int*)d_in[1];
    const int* receivers = (const int*)d_in[2];
    const int* bnodes = (const int*)d_in[3];
    const float* dmean = (const float*)d_in[4];
    const float* dstd = (const float*)d_in[5];
    const float* eW = (const float*)d_in[6];
    const float* eb = (const float*)d_in[7];
    const float* W1 = (const float*)d_in[8];
    const float* A1 = (const float*)d_in[9];
    const float* gamma1 = (const float*)d_in[10];
    const float* beta1 = (const float*)d_in[11];
    const float* W2 = (const float*)d_in[12];
    const float* A2 = (const float*)d_in[13];
    const float* gamma2 = (const float*)d_in[14];
    const float* beta2 = (const float*)d_in[15];
    const float* W3 = (const float*)d_in[16];
    const float* A3 = (const float*)d_in[17];
    const float* dW = (const float*)d_in[18];
    const float* db = (const float*)d_in[19];
    float* out = (float*)d_out;

    char* p = (char*)d_ws;
    auto alloc = [&](size_t b) { char* r = p; p += (b + 255) & ~(size_t)255; return r; };
    float* x_emb = (float*)alloc((size_t)NN * 64 * 4);   // res1
    float* h1 = (float*)alloc((size_t)NN * 64 * 4);      // reused as x1 after gat1
    float* o_raw = (float*)alloc((size_t)NN * 64 * 4);
    float* as1 = (float*)alloc(NN * 4);
    float* ar1 = (float*)alloc(NN * 4);
    int* bid = (int*)alloc(NN * 4);
    unsigned char* isb = (unsigned char*)alloc(NN);
    float* colsum = (float*)alloc(64 * 4);
    float* colsq = (float*)alloc(64 * 4);
    float* mr = (float*)alloc(128 * 4);
    unsigned* mn_ord = (unsigned*)alloc(3 * 4);
    unsigned* mx_ord = (unsigned*)alloc(3 * 4);
    unsigned* cnt = (unsigned*)alloc((size_t)NCOARSE * NCOARSE * 4);
    unsigned* cntr = (unsigned*)alloc((size_t)NREP * NCOARSE * NCOARSE * 4);
    float* cnacc = (float*)alloc(NCOARSE * 64 * 4);
    float* x2 = (float*)alloc(NCOARSE * 64 * 4);   // res2
    float* h2 = (float*)alloc(NCOARSE * 64 * 4);
    float* as2 = (float*)alloc(NCOARSE * 4);
    float* ar2 = (float*)alloc(NCOARSE * 4);
    float* gat2 = (float*)alloc(NCOARSE * 64 * 4);
    float* x3 = (float*)alloc(NCOARSE * 64 * 4);   // res3
    float* h3 = (float*)alloc(NCOARSE * 64 * 4);
    float* as3 = (float*)alloc(NCOARSE * 4);
    float* ar3 = (float*)alloc(NCOARSE * 4);
    float* gat3 = (float*)alloc(NCOARSE * 64 * 4);
    unsigned* deg = (unsigned*)alloc(NN * 4);
    unsigned* rowptr = (unsigned*)alloc((NN + 1) * 4);
    unsigned* partial = (unsigned*)alloc(512 * 4);
    int* csr_s = (int*)alloc((size_t)NE * 4);
    int* pairSe = (int*)alloc((size_t)NE * 4);
    int* pairRe = (int*)alloc((size_t)NE * 4);
    unsigned* gcur = (unsigned*)alloc(NBUCK * 4);
    unsigned* deg2r = (unsigned*)alloc((size_t)NREP2 * NCOARSE * 4);
    unsigned* deg2 = (unsigned*)alloc(NCOARSE * 4);
    unsigned* rowptr2 = (unsigned*)alloc((NCOARSE + 1) * 4);
    unsigned* cursor2r = (unsigned*)alloc((size_t)NREP2 * NCOARSE * 4);
    int* csr_n = (int*)alloc(NN * 4);

    hipMemsetAsync(isb, 0, NN, stream);
    hipMemsetAsync(colsum, 0, 64 * 4, stream);
    hipMemsetAsync(colsq, 0, 64 * 4, stream);
    hipMemsetAsync(mn_ord, 0xFF, 12, stream);
    hipMemsetAsync(mx_ord, 0, 12, stream);
    hipMemsetAsync(cntr, 0, (size_t)NREP * NCOARSE * NCOARSE * 4, stream);
    hipMemsetAsync(cnacc, 0, NCOARSE * 64 * 4, stream);
    hipMemsetAsync(deg, 0, NN * 4, stream);
    hipMemsetAsync(deg2r, 0, (size_t)NREP2 * NCOARSE * 4, stream);

    k_scatter<<<(NBN + 255) / 256, 256, 0, stream>>>(bnodes, isb);
    k_embed<<<2048, 256, 0, stream>>>(nodes, isb, dmean, dstd, eW, eb, x_emb);
    k_minmax<<<512, 256, 0, stream>>>(nodes, mn_ord, mx_ord);
    k_bid<<<(NN + 255) / 256, 256, 0, stream>>>(nodes, mn_ord, mx_ord, bid);
    k_deg<<<(NE + 255) / 256, 256, 0, stream>>>(receivers, deg);
    k_scan1<<<NSB, 256, 0, stream>>>(deg, rowptr, partial);
    k_scan2<<<1, 512, 0, stream>>>(partial);
    k_scan3<<<NSB, 256, 0, stream>>>(rowptr, partial);
    k_gcinit<<<1, 256, 0, stream>>>(rowptr, gcur);
    k_pass1<<<(NE + P1TILE - 1) / P1TILE, 256, 0, stream>>>(senders, receivers, gcur, pairSe, pairRe);
    k_pass2<<<NBUCK, 256, 0, stream>>>(rowptr, pairSe, pairRe, csr_s);
    k_deg2<<<(NN + 255) / 256, 256, 0, stream>>>(bid, deg2r);
    k_scanb<<<1, 512, 0, stream>>>(deg2r, rowptr2, cursor2r, deg2);
    k_fill2<<<(NN + 255) / 256, 256, 0, stream>>>(bid, cursor2r, csr_n);
    k_cnt<<<(NE + 255) / 256, 256, 0, stream>>>(senders, receivers, bid, cntr);
    k_cntmerge<<<NCOARSE * NCOARSE / 256, 256, 0, stream>>>(cntr, cnt);
    k_mm<<<2048, 256, 0, stream>>>(x_emb, W1, A1, h1, as1, ar1, NN);
    k_gat1<<<NN / 4, 256, 0, stream>>>(rowptr, csr_s, as1, ar1, h1, o_raw);
    k_stats2<<<512, 256, 0, stream>>>(o_raw, colsum, colsq);
    k_meanvar<<<1, 64, 0, stream>>>(colsum, colsq, mr);
    k_apply<<<NN / 4, 256, 0, stream>>>(o_raw, x_emb, gamma1, beta1, mr, h1);
    k_cnacc<<<NSB, 256, 0, stream>>>(csr_n, bid, h1, cnacc);
    k_cnscale<<<NCOARSE / 4, 256, 0, stream>>>(cnacc, deg2, x2);
    k_mm<<<NCOARSE / 4, 256, 0, stream>>>(x2, W2, A2, h2, as2, ar2, NCOARSE);
    k_cgat<<<NCOARSE, 256, 0, stream>>>(h2, as2, ar2, cnt, gat2);
    k_cnorm<<<64, 64, 0, stream>>>(gat2, gamma2, beta2, x2, x3);
    k_mm<<<NCOARSE / 4, 256, 0, stream>>>(x3, W3, A3, h3, as3, ar3, NCOARSE);
    k_cgat<<<NCOARSE, 256, 0, stream>>>(h3, as3, ar3, cnt, gat3);
    k_final<<<1, 256, 0, stream>>>(gat3, x3, dW, db, out);
}